// Round 5
// baseline (3288.084 us; speedup 1.0000x reference)
//
#include <hip/hip_runtime.h>
#include <cstdint>
#include <cstddef>

namespace {

constexpr int DIMC  = 512;
constexpr int SEQ   = 6085;   // 1 CLS + 78*78
constexpr int NPAD  = 6144;   // padded to multiple of 256
constexpr int PADF  = 59;     // front zero-pad rows
constexpr int LMK   = 256;    // landmarks
constexpr int BHN   = 16;     // B * HEADS
constexpr int KSPL  = 16;     // split-K factor for attn3 PV
constexpr int MPADR = 6016;   // fc1 per-batch padded rows (47*128)

typedef __attribute__((ext_vector_type(8))) short bf8_t;   // 8 bf16 (MFMA A/B frag)
typedef __attribute__((ext_vector_type(4))) float f4_t;    // 4 f32 (MFMA C/D frag)

// XOR-swizzle for [r][32 ushort] (64B-row) tiles — bijective (verified rounds 2-4)
#define SWZB(r, cu) (((((r) << 6) + ((cu) << 1))) ^ (((r) & 7) << 4))

// async global->LDS, 16B per lane; LDS dest is wave-uniform base + lane*16
#define GLDS16(gp, lp) __builtin_amdgcn_global_load_lds( \
    (const __attribute__((address_space(1))) void*)(gp), \
    (__attribute__((address_space(3))) void*)(lp), 16, 0, 0)

__device__ __forceinline__ ushort f2bf(float f) {
    union { float f; uint32_t u; } c{f};
    uint32_t u = c.u;
    return (ushort)((u + 0x7FFFu + ((u >> 16) & 1u)) >> 16);   // RNE
}
__device__ __forceinline__ float bf2f(ushort u) {
    union { uint32_t u; float f; } c{(uint32_t)u << 16};
    return c.f;
}

// ---------------- reduction helpers ----------------
__device__ __forceinline__ float waveSum(float v) {
#pragma unroll
    for (int o = 32; o > 0; o >>= 1) v += __shfl_xor(v, o, 64);
    return v;
}
__device__ __forceinline__ float waveMax(float v) {
#pragma unroll
    for (int o = 32; o > 0; o >>= 1) v = fmaxf(v, __shfl_xor(v, o, 64));
    return v;
}
__device__ __forceinline__ float blockSum256(float v, float* sm) {
    v = waveSum(v);
    __syncthreads();
    if ((threadIdx.x & 63) == 0) sm[threadIdx.x >> 6] = v;
    __syncthreads();
    return sm[0] + sm[1] + sm[2] + sm[3];
}
__device__ __forceinline__ float blockMax256(float v, float* sm) {
    v = waveMax(v);
    __syncthreads();
    if ((threadIdx.x & 63) == 0) sm[threadIdx.x >> 6] = v;
    __syncthreads();
    return fmaxf(fmaxf(sm[0], sm[1]), fmaxf(sm[2], sm[3]));
}

// =====================================================================
// Workhorse bf16 GEMM: C = A[M,K] @ B[N,K]^T  (both K-contiguous bf16).
// 128x128 tile, BK=64, 4 waves (64x64), global_load_lds(16B) staging with
// pre-swizzled source chunks (q ^= r&7), swizzled ds_read_b128 frags.
// EPI: 0 f32 out (+bias,+relu)  1 bf16 out  2 qkv split-scatter (q*0.125)
//      3 ot scatter (bf16, per-z head layout)
// Staging is UNGUARDED: all A/B buffers must be padded to 128-row tiles.
// =====================================================================
template<int EPI>
__global__ __launch_bounds__(256)
void gemm_bt(const ushort* __restrict__ A, const ushort* __restrict__ B,
             void* __restrict__ Cv, int M, int N, int K,
             int lda, int ldb, int ldc,
             long long sA, long long sB, long long sC,
             const float* __restrict__ bias, int relu,
             ushort* __restrict__ qp, ushort* __restrict__ kp, ushort* __restrict__ vp)
{
    __shared__ __align__(16) char As_s[128 * 128];
    __shared__ __align__(16) char Bs_s[128 * 128];
    const int z = blockIdx.z;
    const ushort* Ab = A + (size_t)z * sA;
    const ushort* Bb = B + (size_t)z * sB;
    const int row0 = blockIdx.y * 128, col0 = blockIdx.x * 128;
    const int tid = threadIdx.x, wid = tid >> 6, lane = tid & 63;
    const int wr = wid >> 1, wc = wid & 1, lr = lane & 15, kg = lane >> 4;
    const int srow = lane >> 3, sq = lane & 7;
    f4_t acc[4][4] = {};
    for (int k0 = 0; k0 < K; k0 += 64) {
        __syncthreads();            // protect LDS from overwrite
#pragma unroll
        for (int i = 0; i < 4; ++i) {
            int r = wid * 32 + i * 8 + srow;
            int qs = sq ^ (r & 7);
            GLDS16(Ab + (size_t)(row0 + r) * lda + k0 + qs * 8,
                   As_s + (wid * 32 + i * 8) * 128);
        }
#pragma unroll
        for (int i = 0; i < 4; ++i) {
            int r = wid * 32 + i * 8 + srow;
            int qs = sq ^ (r & 7);
            GLDS16(Bb + (size_t)(col0 + r) * ldb + k0 + qs * 8,
                   Bs_s + (wid * 32 + i * 8) * 128);
        }
        asm volatile("s_waitcnt vmcnt(0)" ::: "memory");
        __syncthreads();
#pragma unroll
        for (int ks = 0; ks < 2; ++ks) {
            bf8_t af[4], bg[4];
#pragma unroll
            for (int mr = 0; mr < 4; ++mr) {
                int r = wr * 64 + mr * 16 + lr;
                af[mr] = *(const bf8_t*)(As_s + r * 128 + ((((ks << 2) | kg) ^ (r & 7)) << 4));
            }
#pragma unroll
            for (int nr = 0; nr < 4; ++nr) {
                int r = wc * 64 + nr * 16 + lr;
                bg[nr] = *(const bf8_t*)(Bs_s + r * 128 + ((((ks << 2) | kg) ^ (r & 7)) << 4));
            }
#pragma unroll
            for (int mr = 0; mr < 4; ++mr)
#pragma unroll
                for (int nr = 0; nr < 4; ++nr)
                    acc[mr][nr] = __builtin_amdgcn_mfma_f32_16x16x32_bf16(af[mr], bg[nr], acc[mr][nr], 0, 0, 0);
        }
    }
    // ---- epilogue ----
#pragma unroll
    for (int mr = 0; mr < 4; ++mr) {
#pragma unroll
        for (int nr = 0; nr < 4; ++nr) {
#pragma unroll
            for (int r = 0; r < 4; ++r) {
                int gm = row0 + wr * 64 + mr * 16 + kg * 4 + r;
                int gn = col0 + wc * 64 + nr * 16 + lr;
                if (gm >= M || gn >= N) continue;
                float val = acc[mr][nr][r];
                if (EPI == 0) {
                    if (bias) val += bias[gn];
                    if (relu) val = fmaxf(val, 0.f);
                    ((float*)Cv)[(size_t)z * sC + (size_t)gm * ldc + gn] = val;
                } else if (EPI == 1) {
                    ((ushort*)Cv)[(size_t)z * sC + (size_t)gm * ldc + gn] = f2bf(val);
                } else if (EPI == 2) {
                    int b = (gm >= NPAD) ? 1 : 0;
                    int i = gm - b * NPAD;
                    int which = gn >> 9, hh = (gn >> 6) & 7, d = gn & 63;
                    size_t dst = ((size_t)(b * 8 + hh) * NPAD + i) * 64 + d;
                    if (which == 0)      qp[dst] = f2bf(val * 0.125f);
                    else if (which == 1) kp[dst] = f2bf(val);
                    else                 vp[dst] = f2bf(val);
                } else { // 3: ot[b][i][hh*64+d], z = bh
                    int b = z >> 3, hh = z & 7;
                    ((ushort*)Cv)[((size_t)(b * NPAD + gm)) * DIMC + hh * 64 + gn] = f2bf(val);
                }
            }
        }
    }
}

// =====================================================================
// Fused Newton-Schulz pinv: one workgroup per bh runs init + 6 iterations
// + Wt=(pinv@o2)^T internally. 512 threads (8 waves), each GEMM step is
// 256x256x256 (or x64), A/B staged from global per 32-k tile with reg
// prefetch, MFMA 16x16x32. Ping-pong buffers; every __syncthreads drains
// vmcnt so cross-step global RAW/WAR is safe; per-bh buffers touched only
// by this CU (L1 write-through => own reads coherent).
// MODE: 0 D0=v, D1=cd*I-v   1 D0=cd*I-v   2 D0=0.25v   3 D0^T=v (Wt)
// =====================================================================
template<int NF, int MODE>
__device__ __forceinline__ void ns_step(const ushort* __restrict__ Ag,
                                        const ushort* __restrict__ Bg,
                                        ushort* __restrict__ D0, ushort* __restrict__ D1,
                                        float cd, char* As_s, char* Bs_s)
{
    const int tid = threadIdx.x, wid = tid >> 6, lane = tid & 63;
    const int lr = lane & 15, kg = lane >> 4;
    constexpr int N = NF * 16;
    constexpr int BCH = (NF == 16) ? 2 : 1;     // B chunks per thread
    constexpr int BTOT = 4 * N;                 // total B bf8-chunks per k-tile
    f4_t acc[2][NF];
#pragma unroll
    for (int i = 0; i < 2; ++i)
#pragma unroll
        for (int j = 0; j < NF; ++j) acc[i][j] = (f4_t){0.f, 0.f, 0.f, 0.f};

    __syncthreads();    // prior step's stores drained before our loads

    bf8_t pa[2], pb[BCH];
    // prefetch k-tile 0
#pragma unroll
    for (int i = 0; i < 2; ++i) {
        int cid = i * 512 + tid, m = cid >> 2, kc = (cid & 3) * 8;
        pa[i] = *(const bf8_t*)&Ag[(size_t)m * 256 + kc];
    }
#pragma unroll
    for (int i = 0; i < BCH; ++i) {
        int cid = i * 512 + tid;
        if (cid < BTOT) {
            int k = cid / (N / 8), n0 = (cid % (N / 8)) * 8;
            pb[i] = *(const bf8_t*)&Bg[(size_t)k * N + n0];
        }
    }
    for (int kt = 0; kt < 8; ++kt) {
        __syncthreads();   // LDS free (prev MFMA reads done)
#pragma unroll
        for (int i = 0; i < 2; ++i) {
            int cid = i * 512 + tid, m = cid >> 2, kc = (cid & 3) * 8;
            *(bf8_t*)(As_s + SWZB(m, kc)) = pa[i];
        }
#pragma unroll
        for (int i = 0; i < BCH; ++i) {
            int cid = i * 512 + tid;
            if (cid < BTOT) {
                int k = cid / (N / 8), n0 = (cid % (N / 8)) * 8;
#pragma unroll
                for (int j = 0; j < 8; ++j)
                    *(ushort*)(Bs_s + SWZB(n0 + j, k)) = (ushort)pb[i][j];
            }
        }
        if (kt < 7) {      // prefetch next tile (latency hides under MFMA)
            int k0 = (kt + 1) * 32;
#pragma unroll
            for (int i = 0; i < 2; ++i) {
                int cid = i * 512 + tid, m = cid >> 2, kc = (cid & 3) * 8;
                pa[i] = *(const bf8_t*)&Ag[(size_t)m * 256 + k0 + kc];
            }
#pragma unroll
            for (int i = 0; i < BCH; ++i) {
                int cid = i * 512 + tid;
                if (cid < BTOT) {
                    int k = cid / (N / 8), n0 = (cid % (N / 8)) * 8;
                    pb[i] = *(const bf8_t*)&Bg[(size_t)(k0 + k) * N + n0];
                }
            }
        }
        __syncthreads();
        bf8_t af0 = *(const bf8_t*)(As_s + SWZB(wid * 32 + lr, kg * 8));
        bf8_t af1 = *(const bf8_t*)(As_s + SWZB(wid * 32 + 16 + lr, kg * 8));
#pragma unroll
        for (int nf = 0; nf < NF; ++nf) {
            bf8_t bg = *(const bf8_t*)(Bs_s + SWZB(nf * 16 + lr, kg * 8));
            acc[0][nf] = __builtin_amdgcn_mfma_f32_16x16x32_bf16(af0, bg, acc[0][nf], 0, 0, 0);
            acc[1][nf] = __builtin_amdgcn_mfma_f32_16x16x32_bf16(af1, bg, acc[1][nf], 0, 0, 0);
        }
    }
    __syncthreads();       // all staging reads complete before stores
#pragma unroll
    for (int mf = 0; mf < 2; ++mf)
#pragma unroll
        for (int nf = 0; nf < NF; ++nf)
#pragma unroll
            for (int r = 0; r < 4; ++r) {
                int gm = wid * 32 + mf * 16 + kg * 4 + r;
                int gn = nf * 16 + lr;
                float v = acc[mf][nf][r];
                if (MODE == 0) {
                    D0[(size_t)gm * 256 + gn] = f2bf(v);
                    D1[(size_t)gm * 256 + gn] = f2bf(((gm == gn) ? cd : 0.f) - v);
                } else if (MODE == 1) {
                    D0[(size_t)gm * 256 + gn] = f2bf(((gm == gn) ? cd : 0.f) - v);
                } else if (MODE == 2) {
                    D0[(size_t)gm * 256 + gn] = f2bf(0.25f * v);
                } else {
                    D0[(size_t)gn * 256 + gm] = f2bf(v);
                }
            }
}

__global__ __launch_bounds__(512, 1)
void ns_fused(const ushort* __restrict__ X, const float* __restrict__ scal,
              ushort* __restrict__ Z0, ushort* __restrict__ Z1,
              ushort* __restrict__ Y, ushort* __restrict__ TA, ushort* __restrict__ TB,
              const ushort* __restrict__ o2, ushort* __restrict__ Wt)
{
    __shared__ __align__(16) char As_s[256 * 64];
    __shared__ __align__(16) char Bs_s[256 * 64];
    const int bh = blockIdx.x;
    const size_t off = (size_t)bh << 16;
    const ushort* Xb = X + off;
    ushort* Zc = Z0 + off;
    ushort* Zn = Z1 + off;
    ushort* Yb = Y  + off;
    ushort* Ta = TA + off;
    ushort* Tb = TB + off;
    const ushort* o2b = o2 + ((size_t)bh << 14);
    ushort* Wtb = Wt + (size_t)bh * 128 * 256;
    const int tid = threadIdx.x;
    // init: Zc = X^T / (1.0 * maxcolsum)   (row sums of softmax == 1)
    const float inv = 1.f / scal[0];
    for (int idx = tid; idx < 65536; idx += 512) {
        int c = idx >> 8, r = idx & 255;          // read coalesced along r
        Zc[(size_t)r * 256 + c] = f2bf(bf2f(Xb[(size_t)c * 256 + r]) * inv);
    }
    // 6 Newton-Schulz iterations
    for (int it = 0; it < 6; ++it) {
        ns_step<16, 0>(Xb, Zc, Yb, Ta, 7.f,  As_s, Bs_s);   // Y=X@Zc ; TA=7I-Y
        ns_step<16, 1>(Yb, Ta, Tb, nullptr, 15.f, As_s, Bs_s); // TB=15I-Y@TA
        ns_step<16, 1>(Yb, Tb, Ta, nullptr, 13.f, As_s, Bs_s); // TA=13I-Y@TB
        ns_step<16, 2>(Zc, Ta, Zn, nullptr, 0.f,  As_s, Bs_s); // Zn=0.25*Zc@TA
        ushort* t = Zc; Zc = Zn; Zn = t;
    }
    // Wt = (Zc @ o2)^T
    ns_step<4, 3>(Zc, o2b, Wtb, nullptr, 0.f, As_s, Bs_s);
}

// =====================================================================
// attn3 PV split-K: o2p[split][bh][256][64] = P[256, kslice] @ v[kslice, 64]
// =====================================================================
__global__ __launch_bounds__(256)
void pv_splitk(const ushort* __restrict__ S, const ushort* __restrict__ v,
               float* __restrict__ o2p)
{
    __shared__ __align__(16) char As_s[128 * 64];
    __shared__ __align__(16) char Bs_s[64 * 64];
    const int split = blockIdx.x, mt = blockIdx.y, bh = blockIdx.z;
    const int tid = threadIdx.x;
    const int wid = tid >> 6, lane = tid & 63;
    const int lr = lane & 15, kg = lane >> 4;
    const ushort* Sb = S + (size_t)bh * LMK * NPAD + (size_t)(mt * 128) * NPAD;
    const ushort* vb = v + (size_t)bh * NPAD * 64;
    const int ks0 = split * (NPAD / KSPL);
    f4_t acc[2][4] = {};
    for (int k0 = ks0; k0 < ks0 + NPAD / KSPL; k0 += 32) {
#pragma unroll
        for (int p = 0; p < 2; ++p) {
            int idx = p * 256 + tid;
            int m = idx >> 2, kc = (idx & 3) * 8;
            *(bf8_t*)(As_s + SWZB(m, kc)) = *(const bf8_t*)&Sb[(size_t)m * NPAD + k0 + kc];
        }
#pragma unroll
        for (int p = 0; p < 8; ++p) {
            int kk = p * 4 + (tid >> 6), n = tid & 63;
            *(ushort*)(Bs_s + SWZB(n, kk)) = vb[(size_t)(k0 + kk) * 64 + n];
        }
        __syncthreads();
        bf8_t af[2], bg[4];
#pragma unroll
        for (int i = 0; i < 2; ++i)
            af[i] = *(const bf8_t*)(As_s + SWZB(wid * 32 + i * 16 + lr, kg * 8));
#pragma unroll
        for (int j = 0; j < 4; ++j)
            bg[j] = *(const bf8_t*)(Bs_s + SWZB(j * 16 + lr, kg * 8));
#pragma unroll
        for (int i = 0; i < 2; ++i)
#pragma unroll
            for (int j = 0; j < 4; ++j)
                acc[i][j] = __builtin_amdgcn_mfma_f32_16x16x32_bf16(af[i], bg[j], acc[i][j], 0, 0, 0);
        __syncthreads();
    }
#pragma unroll
    for (int i = 0; i < 2; ++i)
#pragma unroll
        for (int j = 0; j < 4; ++j)
#pragma unroll
            for (int r = 0; r < 4; ++r) {
                int gm = mt * 128 + wid * 32 + i * 16 + kg * 4 + r;
                int gn = j * 16 + lr;
                o2p[((size_t)(split * BHN + bh) * LMK + gm) * 64 + gn] = acc[i][j][r];
            }
}

__global__ void reduce_o2(const float* __restrict__ o2p, ushort* __restrict__ o2) {
    int idx = blockIdx.x * 256 + threadIdx.x;   // < BHN*LMK*64
    int bh = idx >> 14, e = idx & 16383;
    float s = 0.f;
#pragma unroll
    for (int sp = 0; sp < KSPL; ++sp)
        s += o2p[((size_t)(sp * BHN + bh) << 14) + e];
    o2[idx] = f2bf(s);
}

// ---------------- small kernels ----------------
__global__ void cvt_bf16(const float* __restrict__ in, ushort* __restrict__ out, int n8) {
    int i = blockIdx.x * 256 + threadIdx.x;
    if (i >= n8) return;
    float4 a = ((const float4*)in)[i * 2], b = ((const float4*)in)[i * 2 + 1];
    ushort4 lo = { f2bf(a.x), f2bf(a.y), f2bf(a.z), f2bf(a.w) };
    ushort4 hi = { f2bf(b.x), f2bf(b.y), f2bf(b.z), f2bf(b.w) };
    ((ushort4*)out)[i * 2] = lo;
    ((ushort4*)out)[i * 2 + 1] = hi;
}

__global__ void extend_h(float* __restrict__ h, const float* __restrict__ cls) {
    int b = blockIdx.y, bx = blockIdx.x; // 0 -> cls, 1..84 -> copy
    float* hb = h + (size_t)b * SEQ * DIMC;
    for (int c = threadIdx.x; c < DIMC; c += 256) {
        if (bx == 0) hb[c] = cls[c];
        else hb[(size_t)(6000 + bx) * DIMC + c] = hb[(size_t)bx * DIMC + c];
    }
}

__global__ void zero_xp_pad(ushort* __restrict__ xp) {
    int e = blockIdx.x * 256 + threadIdx.x;   // 2*59*512
    int b = e / (PADF * DIMC);
    int rest = e - b * (PADF * DIMC);
    xp[(size_t)b * NPAD * DIMC + rest] = 0;
}

__global__ __launch_bounds__(128)
void ln_to_xp(const float* __restrict__ h, const float* __restrict__ g,
              const float* __restrict__ bb, ushort* __restrict__ xp)
{
    __shared__ float sm[2];
    int r = blockIdx.x;            // 0 .. 2*6085-1
    int b = r / SEQ, i = r - b * SEQ;
    int t = threadIdx.x;
    const float4* row = (const float4*)(h + (size_t)r * DIMC);
    float4 x = row[t];
    float s  = x.x + x.y + x.z + x.w;
    float sq = x.x * x.x + x.y * x.y + x.z * x.z + x.w * x.w;
    s = waveSum(s);
    sq = waveSum(sq);
    int w = t >> 6;
    if ((t & 63) == 0) sm[w] = s;
    __syncthreads();
    float S = sm[0] + sm[1];
    __syncthreads();
    if ((t & 63) == 0) sm[w] = sq;
    __syncthreads();
    float SQ = sm[0] + sm[1];
    float mu = S * (1.f / DIMC);
    float var = SQ * (1.f / DIMC) - mu * mu;
    float rs = rsqrtf(var + 1e-5f);
    float4 gg = ((const float4*)g)[t];
    float4 bv = ((const float4*)bb)[t];
    ushort4 o;
    o.x = f2bf((x.x - mu) * rs * gg.x + bv.x);
    o.y = f2bf((x.y - mu) * rs * gg.y + bv.y);
    o.z = f2bf((x.z - mu) * rs * gg.z + bv.z);
    o.w = f2bf((x.w - mu) * rs * gg.w + bv.w);
    ((ushort4*)(xp + ((size_t)b * NPAD + PADF + i) * DIMC))[t] = o;
}

__global__ void landmark_mean(const ushort* __restrict__ in, ushort* __restrict__ out) {
    int m = blockIdx.x, bh = blockIdx.y, d = threadIdx.x;   // 64 threads
    const ushort* p = in + ((size_t)bh * NPAD + (size_t)m * (NPAD / LMK)) * 64 + d;
    float s = 0.f;
#pragma unroll
    for (int j = 0; j < NPAD / LMK; ++j) s += bf2f(p[(size_t)j * 64]);
    out[((size_t)bh * LMK + m) * 64 + d] = f2bf(s * (1.f / (NPAD / LMK)));
}

__global__ __launch_bounds__(256)
void softmax_bf_wide(ushort* __restrict__ S) {   // bf16, rows of 6144
    __shared__ float sm[4];
    ushort* p = S + (size_t)blockIdx.x * NPAD;
    int t = threadIdx.x;
    float v[24];
    float mx = -1e30f;
#pragma unroll
    for (int j = 0; j < 24; ++j) { v[j] = bf2f(p[j * 256 + t]); mx = fmaxf(mx, v[j]); }
    float bm = blockMax256(mx, sm);
    float s = 0.f;
#pragma unroll
    for (int j = 0; j < 24; ++j) { v[j] = expf(v[j] - bm); s += v[j]; }
    float bs = blockSum256(s, sm);
    float inv = 1.f / bs;
#pragma unroll
    for (int j = 0; j < 24; ++j) p[j * 256 + t] = f2bf(v[j] * inv);
}

__global__ __launch_bounds__(256)
void softmax_bf256(ushort* __restrict__ S) {     // bf16, rows of 256
    __shared__ float sm[4];
    ushort* p = S + (size_t)blockIdx.x * 256;
    int t = threadIdx.x;
    float v = bf2f(p[t]);
    float bm = blockMax256(v, sm);
    float e = expf(v - bm);
    float bs = blockSum256(e, sm);
    p[t] = f2bf(e / bs);
}

// max over (bh, j) of column sums of X[bh][:, j]; 16 blocks -> 16 atomics
__global__ __launch_bounds__(256)
void colsum_max(const ushort* __restrict__ X, float* __restrict__ scal) {
    __shared__ float sm[4];
    int bh = blockIdx.x, t = threadIdx.x;
    const ushort* Xb = X + ((size_t)bh << 16);
    float s = 0.f;
#pragma unroll 8
    for (int i = 0; i < 256; ++i) s += bf2f(Xb[(size_t)i * 256 + t]);
    float m = blockMax256(s, sm);
    if (t == 0) atomicMax((unsigned int*)scal, __float_as_uint(m));
}

// depthwise conv residual with LDS v-tile
__global__ __launch_bounds__(256)
void conv_add(const ushort* __restrict__ v, const float* __restrict__ cw,
              ushort* __restrict__ ot)
{
    __shared__ float w[33];
    __shared__ ushort vt[96][64];
    int bh = blockIdx.y;
    int b = bh >> 3, hh = bh & 7;
    int i0 = blockIdx.x * 64;
    int t = threadIdx.x;
    if (t < 33) w[t] = cw[hh * 33 + t];
    const ushort* vb = v + (size_t)bh * NPAD * 64;
    int d = t & 63;
    for (int rr = t >> 6; rr < 96; rr += 4) {
        int j = i0 - 16 + rr;
        vt[rr][d] = (j >= 0 && j < NPAD) ? vb[(size_t)j * 64 + d] : (ushort)0;
    }
    __syncthreads();
    for (int ii = t >> 6; ii < 64; ii += 4) {
        float acc = 0.f;
#pragma unroll
        for (int kk = 0; kk < 33; ++kk) acc += w[kk] * bf2f(vt[ii + kk][d]);
        size_t off = ((size_t)(b * NPAD + i0 + ii)) * DIMC + hh * 64 + d;
        ot[off] = f2bf(bf2f(ot[off]) + acc);
    }
}

__global__ void residual_add(float* __restrict__ h, const float* __restrict__ y) {
    size_t e = (size_t)blockIdx.x * 256 + threadIdx.x;   // < 2*6085*512
    int c = (int)(e & 511);
    size_t ri = e >> 9;
    int i = (int)(ri % SEQ);
    int b = (int)(ri / SEQ);
    h[e] += y[((size_t)b * NPAD + PADF + i) * DIMC + c];
}

__global__ __launch_bounds__(256)
void final_head(const float* __restrict__ h, const float* __restrict__ g,
                const float* __restrict__ bb, const float* __restrict__ w2,
                const float* __restrict__ b2, float* __restrict__ out)
{
    __shared__ float row[DIMC];
    __shared__ float sm[4];
    int b = blockIdx.x;
    int t = threadIdx.x;
    const float* x = h + (size_t)b * SEQ * DIMC;  // CLS row
    float v0 = x[t], v1 = x[t + 256];
    float S = blockSum256(v0 + v1, sm);
    float SQ = blockSum256(v0 * v0 + v1 * v1, sm);
    float mu = S * (1.f / DIMC);
    float rs = rsqrtf(SQ * (1.f / DIMC) - mu * mu + 1e-5f);
    row[t] = (v0 - mu) * rs * g[t] + bb[t];
    row[t + 256] = (v1 - mu) * rs * g[t + 256] + bb[t + 256];
    __syncthreads();
    if (t < 64) {
        float a0 = 0.f, a1 = 0.f;
        for (int idx = t; idx < DIMC; idx += 64) {
            a0 += row[idx] * w2[idx];
            a1 += row[idx] * w2[DIMC + idx];
        }
        a0 = waveSum(a0);
        a1 = waveSum(a1);
        if (t == 0) {
            out[b * 2 + 0] = a0 + b2[0];
            out[b * 2 + 1] = a1 + b2[1];
        }
    }
}

// ---------------- host helpers ----------------
void bt(int epi, const ushort* A, const ushort* B, void* C, int M, int N, int K,
        int lda, int ldb, int ldc, long long sA, long long sB, long long sC, int batch,
        const float* bias, int relu, ushort* qp, ushort* kp, ushort* vp, hipStream_t s)
{
    dim3 g((N + 127) / 128, (M + 127) / 128, batch), blk(256);
    switch (epi) {
    case 0: gemm_bt<0><<<g, blk, 0, s>>>(A, B, C, M, N, K, lda, ldb, ldc, sA, sB, sC, bias, relu, qp, kp, vp); break;
    case 1: gemm_bt<1><<<g, blk, 0, s>>>(A, B, C, M, N, K, lda, ldb, ldc, sA, sB, sC, bias, relu, qp, kp, vp); break;
    case 2: gemm_bt<2><<<g, blk, 0, s>>>(A, B, C, M, N, K, lda, ldb, ldc, sA, sB, sC, bias, relu, qp, kp, vp); break;
    default: gemm_bt<3><<<g, blk, 0, s>>>(A, B, C, M, N, K, lda, ldb, ldc, sA, sB, sC, bias, relu, qp, kp, vp); break;
    }
}

struct WS {
    float *h, *scal, *o2p, *y;
    ushort *xp, *q, *k, *v, *ql, *kl;
    ushort *datab, *w1b, *qkvwb1, *qkvwb2, *outwb1, *outwb2;
    ushort *X, *Z0, *Z1, *XZ, *TA, *TB;
    ushort *o2b, *Wt, *S, *ot;
};

void nystrom_layer(float* h, const float* lng, const float* lnb,
                   const ushort* qkvwb, const ushort* outwb, const float* outb,
                   const float* convw, const WS& w, hipStream_t s)
{
    const long long SM = (long long)LMK * LMK;
    // LN -> padded xp (bf16)
    zero_xp_pad<<<(2 * PADF * DIMC) / 256, 256, 0, s>>>(w.xp);
    ln_to_xp<<<2 * SEQ, 128, 0, s>>>(h, lng, lnb, w.xp);
    // qkv = xp @ Wqkv^T, fused split-scatter into bf16 q (scaled), k, v
    bt(2, w.xp, qkvwb, nullptr, 2 * NPAD, 3 * DIMC, DIMC, DIMC, DIMC, 0,
       0, 0, 0, 1, nullptr, 0, w.q, w.k, w.v, s);
    landmark_mean<<<dim3(LMK, BHN), 64, 0, s>>>(w.q, w.ql);
    landmark_mean<<<dim3(LMK, BHN), 64, 0, s>>>(w.k, w.kl);
    // attn2 = softmax(q_l @ k_l^T)  -> X bf16
    bt(1, w.ql, w.kl, w.X, LMK, LMK, 64, 64, 64, LMK,
       (long long)LMK * 64, (long long)LMK * 64, SM, BHN, nullptr, 0, nullptr, nullptr, nullptr, s);
    softmax_bf256<<<BHN * LMK, 256, 0, s>>>(w.X);
    hipMemsetAsync(w.scal, 0, 8, s);
    colsum_max<<<BHN, 256, 0, s>>>(w.X, w.scal);
    // ---- attn3 first (o2 feeds the fused NS kernel's Wt step) ----
    bt(1, w.ql, w.k, w.S, LMK, NPAD, 64, 64, 64, NPAD,
       (long long)LMK * 64, (long long)NPAD * 64, (long long)LMK * NPAD, BHN,
       nullptr, 0, nullptr, nullptr, nullptr, s);
    softmax_bf_wide<<<BHN * LMK, 256, 0, s>>>(w.S);
    pv_splitk<<<dim3(KSPL, 2, BHN), 256, 0, s>>>(w.S, w.v, w.o2p);
    reduce_o2<<<BHN * LMK * 64 / 256, 256, 0, s>>>(w.o2p, w.o2b);
    // ---- fused Newton-Schulz pinv + Wt = (pinv@o2)^T ----
    ns_fused<<<BHN, 512, 0, s>>>(w.X, w.scal, w.Z0, w.Z1, w.XZ, w.TA, w.TB, w.o2b, w.Wt);
    // ---- attn1: S1 = q @ k_l^T (into S region), softmax, ot = P1 @ Wt^T ----
    ushort* S1 = w.S;
    bt(1, w.q, w.kl, S1, NPAD, LMK, 64, 64, 64, LMK,
       (long long)NPAD * 64, (long long)LMK * 64, (long long)NPAD * LMK, BHN,
       nullptr, 0, nullptr, nullptr, nullptr, s);
    softmax_bf256<<<BHN * NPAD, 256, 0, s>>>(S1);
    bt(3, S1, w.Wt, w.ot, NPAD, 64, LMK, LMK, 256, 0,
       (long long)NPAD * LMK, 128 * 256, 0, BHN, nullptr, 0, nullptr, nullptr, nullptr, s);
    // + depthwise conv(v)
    conv_add<<<dim3(NPAD / 64, BHN), 256, 0, s>>>(w.v, convw, w.ot);
    // out proj -> y f32 (overlays S region, S1 dead)
    bt(0, w.ot, outwb, w.y, 2 * NPAD, DIMC, DIMC, DIMC, DIMC, DIMC,
       0, 0, 0, 1, outb, 0, nullptr, nullptr, nullptr, s);
    // h += y[:, PADF:]
    residual_add<<<(2 * SEQ * DIMC) / 256, 256, 0, s>>>(h, w.y);
}

} // namespace

extern "C" void kernel_launch(void* const* d_in, const int* in_sizes, int n_in,
                              void* d_out, int out_size, void* d_ws, size_t ws_size,
                              hipStream_t stream)
{
    (void)in_sizes; (void)n_in; (void)out_size;
    const float* data  = (const float*)d_in[0];
    const float* w1    = (const float*)d_in[1];
    const float* b1    = (const float*)d_in[2];
    const float* cls   = (const float*)d_in[3];
    const float* ln1g  = (const float*)d_in[4];
    const float* ln1b  = (const float*)d_in[5];
    const float* qkv1w = (const float*)d_in[6];
    const float* out1w = (const float*)d_in[7];
    const float* out1b = (const float*)d_in[8];
    const float* conv1 = (const float*)d_in[9];
    const float* ln2g  = (const float*)d_in[10];
    const float* ln2b  = (const float*)d_in[11];
    const float* qkv2w = (const float*)d_in[12];
    const float* out2w = (const float*)d_in[13];
    const float* out2b = (const float*)d_in[14];
    const float* conv2 = (const float*)d_in[15];
    const float* lnfg  = (const float*)d_in[16];
    const float* lnfb  = (const float*)d_in[17];
    const float* w2    = (const float*)d_in[18];
    const float* b2    = (const float*)d_in[19];
    float* out = (float*)d_out;

    if (ws_size < 209473792ull) return;
    char* p = (char*)d_ws;
    auto alloc = [&](size_t bytes) { char* r = p; p += (bytes + 255) & ~(size_t)255; return r; };
    WS w;
    w.h     = (float*)alloc((size_t)2 * SEQ * DIMC * 4);
    w.xp    = (ushort*)alloc((size_t)2 * NPAD * DIMC * 2);
    w.q     = (ushort*)alloc((size_t)BHN * NPAD * 64 * 2);
    w.k     = (ushort*)alloc((size_t)BHN * NPAD * 64 * 2);   // ot overlay
    w.v     = (ushort*)alloc((size_t)BHN * NPAD * 64 * 2);
    w.ql    = (ushort*)alloc((size_t)BHN * LMK * 64 * 2);
    w.kl    = (ushort*)alloc((size_t)BHN * LMK * 64 * 2);
    w.scal  = (float*)alloc(256);
    w.datab = (ushort*)alloc((size_t)2 * MPADR * 1024 * 2);
    w.w1b   = (ushort*)alloc((size_t)512 * 1024 * 2);
    w.qkvwb1= (ushort*)alloc((size_t)1536 * 512 * 2);
    w.qkvwb2= (ushort*)alloc((size_t)1536 * 512 * 2);
    w.outwb1= (ushort*)alloc((size_t)512 * 512 * 2);
    w.outwb2= (ushort*)alloc((size_t)512 * 512 * 2);
    w.X     = (ushort*)alloc((size_t)BHN * LMK * LMK * 2);
    w.Z0    = (ushort*)alloc((size_t)BHN * LMK * LMK * 2);
    w.Z1    = (ushort*)alloc((size_t)BHN * LMK * LMK * 2);
    w.XZ    = (ushort*)alloc((size_t)BHN * LMK * LMK * 2);
    w.TA    = (ushort*)alloc((size_t)BHN * LMK * LMK * 2);
    w.TB    = (ushort*)alloc((size_t)BHN * LMK * LMK * 2);
    w.o2p   = (float*)alloc((size_t)KSPL * BHN * LMK * 64 * 4);
    w.o2b   = (ushort*)alloc((size_t)BHN * LMK * 64 * 2);
    w.Wt    = (ushort*)alloc((size_t)BHN * 128 * 256 * 2);
    w.S     = (ushort*)alloc((size_t)BHN * LMK * NPAD * 2);
    w.y     = (float*)w.S;   // out-proj output overlays S (dead by then)
    w.ot    = w.k;           // ot overlays k (dead after attn3 scores)

    // ---- one-time per-call bf16 conversions ----
    for (int b = 0; b < 2; ++b)
        cvt_bf16<<<3000, 256, 0, stream>>>(data + (size_t)b * 6000 * 1024,
                                           w.datab + (size_t)b * MPADR * 1024, 768000);
    cvt_bf16<<<256, 256, 0, stream>>>(w1, w.w1b, 65536);
    cvt_bf16<<<384, 256, 0, stream>>>(qkv1w, w.qkvwb1, 98304);
    cvt_bf16<<<384, 256, 0, stream>>>(qkv2w, w.qkvwb2, 98304);
    cvt_bf16<<<128, 256, 0, stream>>>(out1w, w.outwb1, 32768);
    cvt_bf16<<<128, 256, 0, stream>>>(out2w, w.outwb2, 32768);

    // fc1: h[b, 1+i, :] = relu(data[b,i,:] @ w1^T + b1)
    bt(0, w.datab, w.w1b, w.h + DIMC, 6000, DIMC, 1024, 1024, 1024, DIMC,
       (long long)MPADR * 1024, 0, (long long)SEQ * DIMC, 2, b1, 1,
       nullptr, nullptr, nullptr, stream);
    extend_h<<<dim3(85, 2), 256, 0, stream>>>(w.h, cls);

    nystrom_layer(w.h, ln1g, ln1b, w.qkvwb1, w.outwb1, out1b, conv1, w, stream);
    nystrom_layer(w.h, ln2g, ln2b, w.qkvwb2, w.outwb2, out2b, conv2, w, stream);

    final_head<<<2, 256, 0, stream>>>(w.h, lnfg, lnfb, w2, b2, out);
}

// Round 6
// 1124.434 us; speedup vs baseline: 2.9242x; 2.9242x over previous
//
#include <hip/hip_runtime.h>
#include <cstdint>
#include <cstddef>

namespace {

constexpr int DIMC  = 512;
constexpr int SEQ   = 6085;   // 1 CLS + 78*78
constexpr int NPAD  = 6144;   // padded to multiple of 256
constexpr int PADF  = 59;     // front zero-pad rows
constexpr int LMK   = 256;    // landmarks
constexpr int BHN   = 16;     // B * HEADS
constexpr int KSPL  = 16;     // split-K factor for attn3 PV
constexpr int MPADR = 6016;   // fc1 per-batch padded rows (47*128)

typedef __attribute__((ext_vector_type(8))) short bf8_t;   // 8 bf16 (MFMA A/B frag)
typedef __attribute__((ext_vector_type(4))) float f4_t;    // 4 f32 (MFMA C/D frag)

// XOR-swizzle for [r][32 ushort] (64B-row) tiles — bijective (verified rounds 2-4)
#define SWZB(r, cu) (((((r) << 6) + ((cu) << 1))) ^ (((r) & 7) << 4))

// async global->LDS, 16B per lane; LDS dest is wave-uniform base + lane*16
#define GLDS16(gp, lp) __builtin_amdgcn_global_load_lds( \
    (const __attribute__((address_space(1))) void*)(gp), \
    (__attribute__((address_space(3))) void*)(lp), 16, 0, 0)

__device__ __forceinline__ ushort f2bf(float f) {
    union { float f; uint32_t u; } c{f};
    uint32_t u = c.u;
    return (ushort)((u + 0x7FFFu + ((u >> 16) & 1u)) >> 16);   // RNE
}
__device__ __forceinline__ float bf2f(ushort u) {
    union { uint32_t u; float f; } c{(uint32_t)u << 16};
    return c.f;
}

// ---------------- reduction helpers ----------------
__device__ __forceinline__ float waveSum(float v) {
#pragma unroll
    for (int o = 32; o > 0; o >>= 1) v += __shfl_xor(v, o, 64);
    return v;
}
__device__ __forceinline__ float waveMax(float v) {
#pragma unroll
    for (int o = 32; o > 0; o >>= 1) v = fmaxf(v, __shfl_xor(v, o, 64));
    return v;
}
__device__ __forceinline__ float blockSum256(float v, float* sm) {
    v = waveSum(v);
    __syncthreads();
    if ((threadIdx.x & 63) == 0) sm[threadIdx.x >> 6] = v;
    __syncthreads();
    return sm[0] + sm[1] + sm[2] + sm[3];
}
__device__ __forceinline__ float blockMax256(float v, float* sm) {
    v = waveMax(v);
    __syncthreads();
    if ((threadIdx.x & 63) == 0) sm[threadIdx.x >> 6] = v;
    __syncthreads();
    return fmaxf(fmaxf(sm[0], sm[1]), fmaxf(sm[2], sm[3]));
}

// =====================================================================
// Workhorse bf16 GEMM: C = A[M,K] @ B[N,K]^T  (both K-contiguous bf16).
// 128x128 tile, BK=64, 4 waves (64x64), global_load_lds(16B) staging with
// pre-swizzled source chunks (q ^= r&7), swizzled ds_read_b128 frags.
// EPI: 0 f32 out (+bias,+relu)  1 bf16 out  2 qkv split-scatter (q*0.125)
//      3 ot scatter (bf16, per-z head layout)
// Staging is UNGUARDED: all A/B buffers must be padded to 128-row tiles.
// =====================================================================
template<int EPI>
__global__ __launch_bounds__(256)
void gemm_bt(const ushort* __restrict__ A, const ushort* __restrict__ B,
             void* __restrict__ Cv, int M, int N, int K,
             int lda, int ldb, int ldc,
             long long sA, long long sB, long long sC,
             const float* __restrict__ bias, int relu,
             ushort* __restrict__ qp, ushort* __restrict__ kp, ushort* __restrict__ vp)
{
    __shared__ __align__(16) char As_s[128 * 128];
    __shared__ __align__(16) char Bs_s[128 * 128];
    const int z = blockIdx.z;
    const ushort* Ab = A + (size_t)z * sA;
    const ushort* Bb = B + (size_t)z * sB;
    const int row0 = blockIdx.y * 128, col0 = blockIdx.x * 128;
    const int tid = threadIdx.x, wid = tid >> 6, lane = tid & 63;
    const int wr = wid >> 1, wc = wid & 1, lr = lane & 15, kg = lane >> 4;
    const int srow = lane >> 3, sq = lane & 7;
    f4_t acc[4][4] = {};
    for (int k0 = 0; k0 < K; k0 += 64) {
        __syncthreads();            // protect LDS from overwrite
#pragma unroll
        for (int i = 0; i < 4; ++i) {
            int r = wid * 32 + i * 8 + srow;
            int qs = sq ^ (r & 7);
            GLDS16(Ab + (size_t)(row0 + r) * lda + k0 + qs * 8,
                   As_s + (wid * 32 + i * 8) * 128);
        }
#pragma unroll
        for (int i = 0; i < 4; ++i) {
            int r = wid * 32 + i * 8 + srow;
            int qs = sq ^ (r & 7);
            GLDS16(Bb + (size_t)(col0 + r) * ldb + k0 + qs * 8,
                   Bs_s + (wid * 32 + i * 8) * 128);
        }
        asm volatile("s_waitcnt vmcnt(0)" ::: "memory");
        __syncthreads();
#pragma unroll
        for (int ks = 0; ks < 2; ++ks) {
            bf8_t af[4], bg[4];
#pragma unroll
            for (int mr = 0; mr < 4; ++mr) {
                int r = wr * 64 + mr * 16 + lr;
                af[mr] = *(const bf8_t*)(As_s + r * 128 + ((((ks << 2) | kg) ^ (r & 7)) << 4));
            }
#pragma unroll
            for (int nr = 0; nr < 4; ++nr) {
                int r = wc * 64 + nr * 16 + lr;
                bg[nr] = *(const bf8_t*)(Bs_s + r * 128 + ((((ks << 2) | kg) ^ (r & 7)) << 4));
            }
#pragma unroll
            for (int mr = 0; mr < 4; ++mr)
#pragma unroll
                for (int nr = 0; nr < 4; ++nr)
                    acc[mr][nr] = __builtin_amdgcn_mfma_f32_16x16x32_bf16(af[mr], bg[nr], acc[mr][nr], 0, 0, 0);
        }
    }
    // ---- epilogue ----
#pragma unroll
    for (int mr = 0; mr < 4; ++mr) {
#pragma unroll
        for (int nr = 0; nr < 4; ++nr) {
#pragma unroll
            for (int r = 0; r < 4; ++r) {
                int gm = row0 + wr * 64 + mr * 16 + kg * 4 + r;
                int gn = col0 + wc * 64 + nr * 16 + lr;
                if (gm >= M || gn >= N) continue;
                float val = acc[mr][nr][r];
                if (EPI == 0) {
                    if (bias) val += bias[gn];
                    if (relu) val = fmaxf(val, 0.f);
                    ((float*)Cv)[(size_t)z * sC + (size_t)gm * ldc + gn] = val;
                } else if (EPI == 1) {
                    ((ushort*)Cv)[(size_t)z * sC + (size_t)gm * ldc + gn] = f2bf(val);
                } else if (EPI == 2) {
                    int b = (gm >= NPAD) ? 1 : 0;
                    int i = gm - b * NPAD;
                    int which = gn >> 9, hh = (gn >> 6) & 7, d = gn & 63;
                    size_t dst = ((size_t)(b * 8 + hh) * NPAD + i) * 64 + d;
                    if (which == 0)      qp[dst] = f2bf(val * 0.125f);
                    else if (which == 1) kp[dst] = f2bf(val);
                    else                 vp[dst] = f2bf(val);
                } else { // 3: ot[b][i][hh*64+d], z = bh
                    int b = z >> 3, hh = z & 7;
                    ((ushort*)Cv)[((size_t)(b * NPAD + gm)) * DIMC + hh * 64 + gn] = f2bf(val);
                }
            }
        }
    }
}

// =====================================================================
// Small bf16 GEMM for Newton-Schulz: bf16 in/out, f32 accum.
// C = alpha*(A@B) [opt], C2 = c2d*I - alpha*A@B [opt], CT = (alpha*A@B)^T [opt].
// A [M][K] bf16 (lda=K), B [K][N] bf16 (ldb=N). 64x64 tile, 4 waves.
// =====================================================================
__global__ __launch_bounds__(256)
void gemm_ns(const ushort* __restrict__ A, const ushort* __restrict__ B,
             ushort* __restrict__ C, ushort* __restrict__ C2, ushort* __restrict__ CT,
             float alpha, float c2d, int K, int N,
             long long sA, long long sB, long long sC, long long sCT)
{
    __shared__ __align__(16) char As_s[64 * 64];
    __shared__ __align__(16) char Bs_s[64 * 64];
    const int z = blockIdx.z;
    const int row0 = blockIdx.y * 64, col0 = blockIdx.x * 64;
    const int tid = threadIdx.x;
    const int wid = tid >> 6, lane = tid & 63;
    const int lr = lane & 15, kg = lane >> 4;
    const ushort* Ab = A + (size_t)z * sA;
    const ushort* Bb = B + (size_t)z * sB;
    f4_t acc[4] = {};
    const int am = tid >> 2, ac8 = (tid & 3) * 8;
    for (int k0 = 0; k0 < K; k0 += 32) {
        *(bf8_t*)(As_s + SWZB(am, ac8)) = *(const bf8_t*)&Ab[(size_t)(row0 + am) * K + k0 + ac8];
#pragma unroll
        for (int p = 0; p < 8; ++p) {
            int kk = p * 4 + (tid >> 6), n = tid & 63;
            *(ushort*)(Bs_s + SWZB(n, kk)) = Bb[(size_t)(k0 + kk) * N + col0 + n];
        }
        __syncthreads();
        bf8_t af = *(const bf8_t*)(As_s + SWZB(wid * 16 + lr, kg * 8));
#pragma unroll
        for (int j = 0; j < 4; ++j) {
            bf8_t bg = *(const bf8_t*)(Bs_s + SWZB(j * 16 + lr, kg * 8));
            acc[j] = __builtin_amdgcn_mfma_f32_16x16x32_bf16(af, bg, acc[j], 0, 0, 0);
        }
        __syncthreads();
    }
#pragma unroll
    for (int j = 0; j < 4; ++j) {
#pragma unroll
        for (int r = 0; r < 4; ++r) {
            int gm = row0 + wid * 16 + kg * 4 + r;
            int gn = col0 + j * 16 + lr;
            float val = alpha * acc[j][r];
            if (C)  C[(size_t)z * sC + (size_t)gm * N + gn] = f2bf(val);
            if (C2) C2[(size_t)z * sC + (size_t)gm * N + gn] = f2bf(((gm == gn) ? c2d : 0.f) - val);
            if (CT) CT[(size_t)z * sCT + (size_t)gn * LMK + gm] = f2bf(val);
        }
    }
}

// =====================================================================
// attn3 PV split-K: o2p[split][bh][256][64] = P[256, kslice] @ v[kslice, 64]
// =====================================================================
__global__ __launch_bounds__(256)
void pv_splitk(const ushort* __restrict__ S, const ushort* __restrict__ v,
               float* __restrict__ o2p)
{
    __shared__ __align__(16) char As_s[128 * 64];
    __shared__ __align__(16) char Bs_s[64 * 64];
    const int split = blockIdx.x, mt = blockIdx.y, bh = blockIdx.z;
    const int tid = threadIdx.x;
    const int wid = tid >> 6, lane = tid & 63;
    const int lr = lane & 15, kg = lane >> 4;
    const ushort* Sb = S + (size_t)bh * LMK * NPAD + (size_t)(mt * 128) * NPAD;
    const ushort* vb = v + (size_t)bh * NPAD * 64;
    const int ks0 = split * (NPAD / KSPL);
    f4_t acc[2][4] = {};
    for (int k0 = ks0; k0 < ks0 + NPAD / KSPL; k0 += 32) {
#pragma unroll
        for (int p = 0; p < 2; ++p) {
            int idx = p * 256 + tid;
            int m = idx >> 2, kc = (idx & 3) * 8;
            *(bf8_t*)(As_s + SWZB(m, kc)) = *(const bf8_t*)&Sb[(size_t)m * NPAD + k0 + kc];
        }
#pragma unroll
        for (int p = 0; p < 8; ++p) {
            int kk = p * 4 + (tid >> 6), n = tid & 63;
            *(ushort*)(Bs_s + SWZB(n, kk)) = vb[(size_t)(k0 + kk) * 64 + n];
        }
        __syncthreads();
        bf8_t af[2], bg[4];
#pragma unroll
        for (int i = 0; i < 2; ++i)
            af[i] = *(const bf8_t*)(As_s + SWZB(wid * 32 + i * 16 + lr, kg * 8));
#pragma unroll
        for (int j = 0; j < 4; ++j)
            bg[j] = *(const bf8_t*)(Bs_s + SWZB(j * 16 + lr, kg * 8));
#pragma unroll
        for (int i = 0; i < 2; ++i)
#pragma unroll
            for (int j = 0; j < 4; ++j)
                acc[i][j] = __builtin_amdgcn_mfma_f32_16x16x32_bf16(af[i], bg[j], acc[i][j], 0, 0, 0);
        __syncthreads();
    }
#pragma unroll
    for (int i = 0; i < 2; ++i)
#pragma unroll
        for (int j = 0; j < 4; ++j)
#pragma unroll
            for (int r = 0; r < 4; ++r) {
                int gm = mt * 128 + wid * 32 + i * 16 + kg * 4 + r;
                int gn = j * 16 + lr;
                o2p[((size_t)(split * BHN + bh) * LMK + gm) * 64 + gn] = acc[i][j][r];
            }
}

__global__ void reduce_o2(const float* __restrict__ o2p, ushort* __restrict__ o2) {
    int idx = blockIdx.x * 256 + threadIdx.x;   // < BHN*LMK*64
    int bh = idx >> 14, e = idx & 16383;
    float s = 0.f;
#pragma unroll
    for (int sp = 0; sp < KSPL; ++sp)
        s += o2p[((size_t)(sp * BHN + bh) << 14) + e];
    o2[idx] = f2bf(s);
}

// ---------------- small kernels ----------------
__global__ void cvt_bf16(const float* __restrict__ in, ushort* __restrict__ out, int n8) {
    int i = blockIdx.x * 256 + threadIdx.x;
    if (i >= n8) return;
    float4 a = ((const float4*)in)[i * 2], b = ((const float4*)in)[i * 2 + 1];
    ushort4 lo = { f2bf(a.x), f2bf(a.y), f2bf(a.z), f2bf(a.w) };
    ushort4 hi = { f2bf(b.x), f2bf(b.y), f2bf(b.z), f2bf(b.w) };
    ((ushort4*)out)[i * 2] = lo;
    ((ushort4*)out)[i * 2 + 1] = hi;
}

__global__ void extend_h(float* __restrict__ h, const float* __restrict__ cls) {
    int b = blockIdx.y, bx = blockIdx.x; // 0 -> cls, 1..84 -> copy
    float* hb = h + (size_t)b * SEQ * DIMC;
    for (int c = threadIdx.x; c < DIMC; c += 256) {
        if (bx == 0) hb[c] = cls[c];
        else hb[(size_t)(6000 + bx) * DIMC + c] = hb[(size_t)bx * DIMC + c];
    }
}

__global__ void zero_xp_pad(ushort* __restrict__ xp) {
    int e = blockIdx.x * 256 + threadIdx.x;   // 2*59*512
    int b = e / (PADF * DIMC);
    int rest = e - b * (PADF * DIMC);
    xp[(size_t)b * NPAD * DIMC + rest] = 0;
}

__global__ __launch_bounds__(128)
void ln_to_xp(const float* __restrict__ h, const float* __restrict__ g,
              const float* __restrict__ bb, ushort* __restrict__ xp)
{
    __shared__ float sm[2];
    int r = blockIdx.x;            // 0 .. 2*6085-1
    int b = r / SEQ, i = r - b * SEQ;
    int t = threadIdx.x;
    const float4* row = (const float4*)(h + (size_t)r * DIMC);
    float4 x = row[t];
    float s  = x.x + x.y + x.z + x.w;
    float sq = x.x * x.x + x.y * x.y + x.z * x.z + x.w * x.w;
    s = waveSum(s);
    sq = waveSum(sq);
    int w = t >> 6;
    if ((t & 63) == 0) sm[w] = s;
    __syncthreads();
    float S = sm[0] + sm[1];
    __syncthreads();
    if ((t & 63) == 0) sm[w] = sq;
    __syncthreads();
    float SQ = sm[0] + sm[1];
    float mu = S * (1.f / DIMC);
    float var = SQ * (1.f / DIMC) - mu * mu;
    float rs = rsqrtf(var + 1e-5f);
    float4 gg = ((const float4*)g)[t];
    float4 bv = ((const float4*)bb)[t];
    ushort4 o;
    o.x = f2bf((x.x - mu) * rs * gg.x + bv.x);
    o.y = f2bf((x.y - mu) * rs * gg.y + bv.y);
    o.z = f2bf((x.z - mu) * rs * gg.z + bv.z);
    o.w = f2bf((x.w - mu) * rs * gg.w + bv.w);
    ((ushort4*)(xp + ((size_t)b * NPAD + PADF + i) * DIMC))[t] = o;
}

__global__ void landmark_mean(const ushort* __restrict__ in, ushort* __restrict__ out) {
    int m = blockIdx.x, bh = blockIdx.y, d = threadIdx.x;   // 64 threads
    const ushort* p = in + ((size_t)bh * NPAD + (size_t)m * (NPAD / LMK)) * 64 + d;
    float s = 0.f;
#pragma unroll
    for (int j = 0; j < NPAD / LMK; ++j) s += bf2f(p[(size_t)j * 64]);
    out[((size_t)bh * LMK + m) * 64 + d] = f2bf(s * (1.f / (NPAD / LMK)));
}

__global__ __launch_bounds__(256)
void softmax_bf_wide(ushort* __restrict__ S) {   // bf16, rows of 6144
    __shared__ float sm[4];
    ushort* p = S + (size_t)blockIdx.x * NPAD;
    int t = threadIdx.x;
    float v[24];
    float mx = -1e30f;
#pragma unroll
    for (int j = 0; j < 24; ++j) { v[j] = bf2f(p[j * 256 + t]); mx = fmaxf(mx, v[j]); }
    float bm = blockMax256(mx, sm);
    float s = 0.f;
#pragma unroll
    for (int j = 0; j < 24; ++j) { v[j] = expf(v[j] - bm); s += v[j]; }
    float bs = blockSum256(s, sm);
    float inv = 1.f / bs;
#pragma unroll
    for (int j = 0; j < 24; ++j) p[j * 256 + t] = f2bf(v[j] * inv);
}

__global__ __launch_bounds__(256)
void softmax_bf256(ushort* __restrict__ S) {     // bf16, rows of 256
    __shared__ float sm[4];
    ushort* p = S + (size_t)blockIdx.x * 256;
    int t = threadIdx.x;
    float v = bf2f(p[t]);
    float bm = blockMax256(v, sm);
    float e = expf(v - bm);
    float bs = blockSum256(e, sm);
    p[t] = f2bf(e / bs);
}

// max over (bh, j) of column sums of X[bh][:, j]; 16 blocks -> 16 atomics.
// (row-sum factor of softmax rows is identically 1.0, so only colsum needed)
__global__ __launch_bounds__(256)
void colsum_max(const ushort* __restrict__ X, float* __restrict__ scal) {
    __shared__ float sm[4];
    int bh = blockIdx.x, t = threadIdx.x;
    const ushort* Xb = X + ((size_t)bh << 16);
    float s = 0.f;
#pragma unroll 8
    for (int i = 0; i < 256; ++i) s += bf2f(Xb[(size_t)i * 256 + t]);
    float m = blockMax256(s, sm);
    if (t == 0) atomicMax((unsigned int*)scal, __float_as_uint(m));
}

__global__ void init_z(const ushort* __restrict__ X, const float* __restrict__ scal,
                       ushort* __restrict__ Z) {
    size_t e = (size_t)blockIdx.x * 256 + threadIdx.x;  // < 16*65536
    int c = (int)(e & 255);
    int r = (int)((e >> 8) & 255);
    size_t bh = e >> 16;
    float inv = 1.f / scal[0];
    Z[e] = f2bf(bf2f(X[(bh << 16) + (size_t)c * 256 + r]) * inv);
}

// depthwise conv residual with LDS v-tile
__global__ __launch_bounds__(256)
void conv_add(const ushort* __restrict__ v, const float* __restrict__ cw,
              ushort* __restrict__ ot)
{
    __shared__ float w[33];
    __shared__ ushort vt[96][64];
    int bh = blockIdx.y;
    int b = bh >> 3, hh = bh & 7;
    int i0 = blockIdx.x * 64;
    int t = threadIdx.x;
    if (t < 33) w[t] = cw[hh * 33 + t];
    const ushort* vb = v + (size_t)bh * NPAD * 64;
    int d = t & 63;
    for (int rr = t >> 6; rr < 96; rr += 4) {
        int j = i0 - 16 + rr;
        vt[rr][d] = (j >= 0 && j < NPAD) ? vb[(size_t)j * 64 + d] : (ushort)0;
    }
    __syncthreads();
    for (int ii = t >> 6; ii < 64; ii += 4) {
        float acc = 0.f;
#pragma unroll
        for (int kk = 0; kk < 33; ++kk) acc += w[kk] * bf2f(vt[ii + kk][d]);
        size_t off = ((size_t)(b * NPAD + i0 + ii)) * DIMC + hh * 64 + d;
        ot[off] = f2bf(bf2f(ot[off]) + acc);
    }
}

__global__ void residual_add(float* __restrict__ h, const float* __restrict__ y) {
    size_t e = (size_t)blockIdx.x * 256 + threadIdx.x;   // < 2*6085*512
    int c = (int)(e & 511);
    size_t ri = e >> 9;
    int i = (int)(ri % SEQ);
    int b = (int)(ri / SEQ);
    h[e] += y[((size_t)b * NPAD + PADF + i) * DIMC + c];
}

__global__ __launch_bounds__(256)
void final_head(const float* __restrict__ h, const float* __restrict__ g,
                const float* __restrict__ bb, const float* __restrict__ w2,
                const float* __restrict__ b2, float* __restrict__ out)
{
    __shared__ float row[DIMC];
    __shared__ float sm[4];
    int b = blockIdx.x;
    int t = threadIdx.x;
    const float* x = h + (size_t)b * SEQ * DIMC;  // CLS row
    float v0 = x[t], v1 = x[t + 256];
    float S = blockSum256(v0 + v1, sm);
    float SQ = blockSum256(v0 * v0 + v1 * v1, sm);
    float mu = S * (1.f / DIMC);
    float rs = rsqrtf(SQ * (1.f / DIMC) - mu * mu + 1e-5f);
    row[t] = (v0 - mu) * rs * g[t] + bb[t];
    row[t + 256] = (v1 - mu) * rs * g[t + 256] + bb[t + 256];
    __syncthreads();
    if (t < 64) {
        float a0 = 0.f, a1 = 0.f;
        for (int idx = t; idx < DIMC; idx += 64) {
            a0 += row[idx] * w2[idx];
            a1 += row[idx] * w2[DIMC + idx];
        }
        a0 = waveSum(a0);
        a1 = waveSum(a1);
        if (t == 0) {
            out[b * 2 + 0] = a0 + b2[0];
            out[b * 2 + 1] = a1 + b2[1];
        }
    }
}

// ---------------- host helpers ----------------
void bt(int epi, const ushort* A, const ushort* B, void* C, int M, int N, int K,
        int lda, int ldb, int ldc, long long sA, long long sB, long long sC, int batch,
        const float* bias, int relu, ushort* qp, ushort* kp, ushort* vp, hipStream_t s)
{
    dim3 g((N + 127) / 128, (M + 127) / 128, batch), blk(256);
    switch (epi) {
    case 0: gemm_bt<0><<<g, blk, 0, s>>>(A, B, C, M, N, K, lda, ldb, ldc, sA, sB, sC, bias, relu, qp, kp, vp); break;
    case 1: gemm_bt<1><<<g, blk, 0, s>>>(A, B, C, M, N, K, lda, ldb, ldc, sA, sB, sC, bias, relu, qp, kp, vp); break;
    case 2: gemm_bt<2><<<g, blk, 0, s>>>(A, B, C, M, N, K, lda, ldb, ldc, sA, sB, sC, bias, relu, qp, kp, vp); break;
    default: gemm_bt<3><<<g, blk, 0, s>>>(A, B, C, M, N, K, lda, ldb, ldc, sA, sB, sC, bias, relu, qp, kp, vp); break;
    }
}

void ns(const ushort* A, const ushort* B, ushort* C, ushort* C2, ushort* CT,
        float alpha, float c2d, int M, int N, int K,
        long long sA, long long sB, long long sC, long long sCT, hipStream_t s)
{
    dim3 g(N / 64, M / 64, BHN), blk(256);
    gemm_ns<<<g, blk, 0, s>>>(A, B, C, C2, CT, alpha, c2d, K, N, sA, sB, sC, sCT);
}

struct WS {
    float *h, *scal, *o2p, *y;
    ushort *xp, *q, *k, *v, *ql, *kl;
    ushort *datab, *w1b, *qkvwb1, *qkvwb2, *outwb1, *outwb2;
    ushort *X, *Z0, *Z1, *XZ, *TA, *TB, *TC;
    ushort *o2b, *Wt, *S, *ot;
};

void nystrom_layer(float* h, const float* lng, const float* lnb,
                   const ushort* qkvwb, const ushort* outwb, const float* outb,
                   const float* convw, const WS& w, hipStream_t s)
{
    const long long SM = (long long)LMK * LMK;
    // LN -> padded xp (bf16)
    zero_xp_pad<<<(2 * PADF * DIMC) / 256, 256, 0, s>>>(w.xp);
    ln_to_xp<<<2 * SEQ, 128, 0, s>>>(h, lng, lnb, w.xp);
    // qkv = xp @ Wqkv^T, fused split-scatter into bf16 q (scaled), k, v
    bt(2, w.xp, qkvwb, nullptr, 2 * NPAD, 3 * DIMC, DIMC, DIMC, DIMC, 0,
       0, 0, 0, 1, nullptr, 0, w.q, w.k, w.v, s);
    landmark_mean<<<dim3(LMK, BHN), 64, 0, s>>>(w.q, w.ql);
    landmark_mean<<<dim3(LMK, BHN), 64, 0, s>>>(w.k, w.kl);
    // attn2 = softmax(q_l @ k_l^T)  -> X bf16
    bt(1, w.ql, w.kl, w.X, LMK, LMK, 64, 64, 64, LMK,
       (long long)LMK * 64, (long long)LMK * 64, SM, BHN, nullptr, 0, nullptr, nullptr, nullptr, s);
    softmax_bf256<<<BHN * LMK, 256, 0, s>>>(w.X);
    hipMemsetAsync(w.scal, 0, 8, s);
    colsum_max<<<BHN, 256, 0, s>>>(w.X, w.scal);
    init_z<<<(BHN * LMK * LMK) / 256, 256, 0, s>>>(w.X, w.scal, w.Z0);
    // Newton-Schulz (batched bf16 MFMA, diag fused)
    ushort* Zc = w.Z0;
    ushort* Zn = w.Z1;
    for (int it = 0; it < 6; ++it) {
        ns(w.X, Zc, w.XZ, w.TA, nullptr, 1.f, 7.f, LMK, LMK, LMK, SM, SM, SM, 0, s);
        ns(w.XZ, w.TA, w.TB, w.TC, nullptr, 1.f, 15.f, LMK, LMK, LMK, SM, SM, SM, 0, s);
        ns(w.XZ, w.TC, w.TB, w.TA, nullptr, 1.f, 13.f, LMK, LMK, LMK, SM, SM, SM, 0, s);
        ns(Zc, w.TA, Zn, nullptr, nullptr, 0.25f, 0.f, LMK, LMK, LMK, SM, SM, SM, 0, s);
        ushort* t = Zc; Zc = Zn; Zn = t;
    }
    // ---- attn3: S = q_l @ k^T (bf16), softmax, o2 = P @ v (split-K) ----
    bt(1, w.ql, w.k, w.S, LMK, NPAD, 64, 64, 64, NPAD,
       (long long)LMK * 64, (long long)NPAD * 64, (long long)LMK * NPAD, BHN,
       nullptr, 0, nullptr, nullptr, nullptr, s);
    softmax_bf_wide<<<BHN * LMK, 256, 0, s>>>(w.S);
    pv_splitk<<<dim3(KSPL, 2, BHN), 256, 0, s>>>(w.S, w.v, w.o2p);
    reduce_o2<<<BHN * LMK * 64 / 256, 256, 0, s>>>(w.o2p, w.o2b);
    // Wt = (pinv @ o2)^T  (bf16, padded to 128 rows per bh)
    ns(Zc, w.o2b, nullptr, nullptr, w.Wt, 1.f, 0.f, LMK, 64, LMK,
       SM, (long long)LMK * 64, 0, 128 * 256, s);
    // ---- attn1: S1 = q @ k_l^T (into S region), softmax, ot = P1 @ Wt^T ----
    ushort* S1 = w.S;
    bt(1, w.q, w.kl, S1, NPAD, LMK, 64, 64, 64, LMK,
       (long long)NPAD * 64, (long long)LMK * 64, (long long)NPAD * LMK, BHN,
       nullptr, 0, nullptr, nullptr, nullptr, s);
    softmax_bf256<<<BHN * NPAD, 256, 0, s>>>(S1);
    bt(3, S1, w.Wt, w.ot, NPAD, 64, LMK, LMK, 256, 0,
       (long long)NPAD * LMK, 128 * 256, 0, BHN, nullptr, 0, nullptr, nullptr, nullptr, s);
    // + depthwise conv(v)
    conv_add<<<dim3(NPAD / 64, BHN), 256, 0, s>>>(w.v, convw, w.ot);
    // out proj -> y f32 (overlays S region, S1 dead)
    bt(0, w.ot, outwb, w.y, 2 * NPAD, DIMC, DIMC, DIMC, DIMC, DIMC,
       0, 0, 0, 1, outb, 0, nullptr, nullptr, nullptr, s);
    // h += y[:, PADF:]
    residual_add<<<(2 * SEQ * DIMC) / 256, 256, 0, s>>>(h, w.y);
}

} // namespace

extern "C" void kernel_launch(void* const* d_in, const int* in_sizes, int n_in,
                              void* d_out, int out_size, void* d_ws, size_t ws_size,
                              hipStream_t stream)
{
    (void)in_sizes; (void)n_in; (void)out_size;
    const float* data  = (const float*)d_in[0];
    const float* w1    = (const float*)d_in[1];
    const float* b1    = (const float*)d_in[2];
    const float* cls   = (const float*)d_in[3];
    const float* ln1g  = (const float*)d_in[4];
    const float* ln1b  = (const float*)d_in[5];
    const float* qkv1w = (const float*)d_in[6];
    const float* out1w = (const float*)d_in[7];
    const float* out1b = (const float*)d_in[8];
    const float* conv1 = (const float*)d_in[9];
    const float* ln2g  = (const float*)d_in[10];
    const float* ln2b  = (const float*)d_in[11];
    const float* qkv2w = (const float*)d_in[12];
    const float* out2w = (const float*)d_in[13];
    const float* out2b = (const float*)d_in[14];
    const float* conv2 = (const float*)d_in[15];
    const float* lnfg  = (const float*)d_in[16];
    const float* lnfb  = (const float*)d_in[17];
    const float* w2    = (const float*)d_in[18];
    const float* b2    = (const float*)d_in[19];
    float* out = (float*)d_out;

    if (ws_size < 209473792ull) return;
    char* p = (char*)d_ws;
    auto alloc = [&](size_t bytes) { char* r = p; p += (bytes + 255) & ~(size_t)255; return r; };
    WS w;
    w.h     = (float*)alloc((size_t)2 * SEQ * DIMC * 4);
    w.xp    = (ushort*)alloc((size_t)2 * NPAD * DIMC * 2);
    w.q     = (ushort*)alloc((size_t)BHN * NPAD * 64 * 2);
    w.k     = (ushort*)alloc((size_t)BHN * NPAD * 64 * 2);   // ot overlay
    w.v     = (ushort*)alloc((size_t)BHN * NPAD * 64 * 2);
    w.ql    = (ushort*)alloc((size_t)BHN * LMK * 64 * 2);
    w.kl    = (ushort*)alloc((size_t)BHN * LMK * 64 * 2);
    w.scal  = (float*)alloc(256);
    w.datab = (ushort*)alloc((size_t)2 * MPADR * 1024 * 2);
    w.w1b   = (ushort*)alloc((size_t)512 * 1024 * 2);
    w.qkvwb1= (ushort*)alloc((size_t)1536 * 512 * 2);
    w.qkvwb2= (ushort*)alloc((size_t)1536 * 512 * 2);
    w.outwb1= (ushort*)alloc((size_t)512 * 512 * 2);
    w.outwb2= (ushort*)alloc((size_t)512 * 512 * 2);
    w.X     = (ushort*)alloc((size_t)BHN * LMK * LMK * 2);
    w.Z0    = (ushort*)alloc((size_t)BHN * LMK * LMK * 2);
    w.Z1    = (ushort*)alloc((size_t)BHN * LMK * LMK * 2);
    w.XZ    = (ushort*)alloc((size_t)BHN * LMK * LMK * 2);
    w.TA    = (ushort*)alloc((size_t)BHN * LMK * LMK * 2);
    w.TB    = (ushort*)alloc((size_t)BHN * LMK * LMK * 2);
    w.TC    = (ushort*)alloc((size_t)BHN * LMK * LMK * 2);
    w.o2p   = (float*)alloc((size_t)KSPL * BHN * LMK * 64 * 4);
    w.o2b   = (ushort*)alloc((size_t)BHN * LMK * 64 * 2);
    w.Wt    = (ushort*)alloc((size_t)BHN * 128 * 256 * 2);
    w.S     = (ushort*)alloc((size_t)BHN * LMK * NPAD * 2);
    w.y     = (float*)w.S;   // out-proj output overlays S (dead by then)
    w.ot    = w.k;           // ot overlays k (dead after attn3 scores)

    // ---- one-time per-call bf16 conversions ----
    for (int b = 0; b < 2; ++b)
        cvt_bf16<<<3000, 256, 0, stream>>>(data + (size_t)b * 6000 * 1024,
                                           w.datab + (size_t)b * MPADR * 1024, 768000);
    cvt_bf16<<<256, 256, 0, stream>>>(w1, w.w1b, 65536);
    cvt_bf16<<<384, 256, 0, stream>>>(qkv1w, w.qkvwb1, 98304);
    cvt_bf16<<<384, 256, 0, stream>>>(qkv2w, w.qkvwb2, 98304);
    cvt_bf16<<<128, 256, 0, stream>>>(out1w, w.outwb1, 32768);
    cvt_bf16<<<128, 256, 0, stream>>>(out2w, w.outwb2, 32768);

    // fc1: h[b, 1+i, :] = relu(data[b,i,:] @ w1^T + b1)
    bt(0, w.datab, w.w1b, w.h + DIMC, 6000, DIMC, 1024, 1024, 1024, DIMC,
       (long long)MPADR * 1024, 0, (long long)SEQ * DIMC, 2, b1, 1,
       nullptr, nullptr, nullptr, stream);
    extend_h<<<dim3(85, 2), 256, 0, stream>>>(w.h, cls);

    nystrom_layer(w.h, ln1g, ln1b, w.qkvwb1, w.outwb1, out1b, conv1, w, stream);
    nystrom_layer(w.h, ln2g, ln2b, w.qkvwb2, w.outwb2, out2b, conv2, w, stream);

    final_head<<<2, 256, 0, stream>>>(w.h, lnfg, lnfb, w2, b2, out);
}

// Round 7
// 1019.273 us; speedup vs baseline: 3.2259x; 1.1032x over previous
//
#include <hip/hip_runtime.h>
#include <cstdint>
#include <cstddef>

namespace {

constexpr int DIMC  = 512;
constexpr int SEQ   = 6085;   // 1 CLS + 78*78
constexpr int NPAD  = 6144;   // padded to multiple of 256
constexpr int PADF  = 59;     // front zero-pad rows
constexpr int LMK   = 256;    // landmarks
constexpr int BHN   = 16;     // B * HEADS
constexpr int KSPL  = 16;     // split-K factor for attn3 PV
constexpr int MPADR = 6016;   // fc1 per-batch padded rows (47*128)

typedef __attribute__((ext_vector_type(8))) short bf8_t;   // 8 bf16 (MFMA A/B frag)
typedef __attribute__((ext_vector_type(4))) float f4_t;    // 4 f32 (MFMA C/D frag)

// XOR-swizzle for [r][32 ushort] (64B-row) tiles — bijective (verified rounds 2-4)
#define SWZB(r, cu) (((((r) << 6) + ((cu) << 1))) ^ (((r) & 7) << 4))

// async global->LDS, 16B per lane; LDS dest is wave-uniform base + lane*16
#define GLDS16(gp, lp) __builtin_amdgcn_global_load_lds( \
    (const __attribute__((address_space(1))) void*)(gp), \
    (__attribute__((address_space(3))) void*)(lp), 16, 0, 0)

__device__ __forceinline__ ushort f2bf(float f) {
    union { float f; uint32_t u; } c{f};
    uint32_t u = c.u;
    return (ushort)((u + 0x7FFFu + ((u >> 16) & 1u)) >> 16);   // RNE
}
__device__ __forceinline__ float bf2f(ushort u) {
    union { uint32_t u; float f; } c{(uint32_t)u << 16};
    return c.f;
}

// ---------------- reduction helpers ----------------
__device__ __forceinline__ float waveSum(float v) {
#pragma unroll
    for (int o = 32; o > 0; o >>= 1) v += __shfl_xor(v, o, 64);
    return v;
}
__device__ __forceinline__ float waveMax(float v) {
#pragma unroll
    for (int o = 32; o > 0; o >>= 1) v = fmaxf(v, __shfl_xor(v, o, 64));
    return v;
}
__device__ __forceinline__ float blockSum256(float v, float* sm) {
    v = waveSum(v);
    __syncthreads();
    if ((threadIdx.x & 63) == 0) sm[threadIdx.x >> 6] = v;
    __syncthreads();
    return sm[0] + sm[1] + sm[2] + sm[3];
}
__device__ __forceinline__ float blockMax256(float v, float* sm) {
    v = waveMax(v);
    __syncthreads();
    if ((threadIdx.x & 63) == 0) sm[threadIdx.x >> 6] = v;
    __syncthreads();
    return fmaxf(fmaxf(sm[0], sm[1]), fmaxf(sm[2], sm[3]));
}

// =====================================================================
// Workhorse bf16 GEMM: C = A[M,K] @ B[N,K]^T  (both K-contiguous bf16).
// 128x128 tile, BK=64, 4 waves (64x64), global_load_lds(16B) staging with
// pre-swizzled source chunks (q ^= r&7), swizzled ds_read_b128 frags.
// EPI: 0 f32 out (+bias,+relu)  1 bf16 out  2 qkv split-scatter (q*0.125)
// Staging is UNGUARDED: all A/B buffers must be padded to 128-row tiles.
// =====================================================================
template<int EPI>
__global__ __launch_bounds__(256)
void gemm_bt(const ushort* __restrict__ A, const ushort* __restrict__ B,
             void* __restrict__ Cv, int M, int N, int K,
             int lda, int ldb, int ldc,
             long long sA, long long sB, long long sC,
             const float* __restrict__ bias, int relu,
             ushort* __restrict__ qp, ushort* __restrict__ kp, ushort* __restrict__ vp)
{
    __shared__ __align__(16) char As_s[128 * 128];
    __shared__ __align__(16) char Bs_s[128 * 128];
    const int z = blockIdx.z;
    const ushort* Ab = A + (size_t)z * sA;
    const ushort* Bb = B + (size_t)z * sB;
    const int row0 = blockIdx.y * 128, col0 = blockIdx.x * 128;
    const int tid = threadIdx.x, wid = tid >> 6, lane = tid & 63;
    const int wr = wid >> 1, wc = wid & 1, lr = lane & 15, kg = lane >> 4;
    const int srow = lane >> 3, sq = lane & 7;
    f4_t acc[4][4] = {};
    for (int k0 = 0; k0 < K; k0 += 64) {
        __syncthreads();            // protect LDS from overwrite
#pragma unroll
        for (int i = 0; i < 4; ++i) {
            int r = wid * 32 + i * 8 + srow;
            int qs = sq ^ (r & 7);
            GLDS16(Ab + (size_t)(row0 + r) * lda + k0 + qs * 8,
                   As_s + (wid * 32 + i * 8) * 128);
        }
#pragma unroll
        for (int i = 0; i < 4; ++i) {
            int r = wid * 32 + i * 8 + srow;
            int qs = sq ^ (r & 7);
            GLDS16(Bb + (size_t)(col0 + r) * ldb + k0 + qs * 8,
                   Bs_s + (wid * 32 + i * 8) * 128);
        }
        asm volatile("s_waitcnt vmcnt(0)" ::: "memory");
        __syncthreads();
#pragma unroll
        for (int ks = 0; ks < 2; ++ks) {
            bf8_t af[4], bg[4];
#pragma unroll
            for (int mr = 0; mr < 4; ++mr) {
                int r = wr * 64 + mr * 16 + lr;
                af[mr] = *(const bf8_t*)(As_s + r * 128 + ((((ks << 2) | kg) ^ (r & 7)) << 4));
            }
#pragma unroll
            for (int nr = 0; nr < 4; ++nr) {
                int r = wc * 64 + nr * 16 + lr;
                bg[nr] = *(const bf8_t*)(Bs_s + r * 128 + ((((ks << 2) | kg) ^ (r & 7)) << 4));
            }
#pragma unroll
            for (int mr = 0; mr < 4; ++mr)
#pragma unroll
                for (int nr = 0; nr < 4; ++nr)
                    acc[mr][nr] = __builtin_amdgcn_mfma_f32_16x16x32_bf16(af[mr], bg[nr], acc[mr][nr], 0, 0, 0);
        }
    }
    // ---- epilogue ----
#pragma unroll
    for (int mr = 0; mr < 4; ++mr) {
#pragma unroll
        for (int nr = 0; nr < 4; ++nr) {
#pragma unroll
            for (int r = 0; r < 4; ++r) {
                int gm = row0 + wr * 64 + mr * 16 + kg * 4 + r;
                int gn = col0 + wc * 64 + nr * 16 + lr;
                if (gm >= M || gn >= N) continue;
                float val = acc[mr][nr][r];
                if (EPI == 0) {
                    if (bias) val += bias[gn];
                    if (relu) val = fmaxf(val, 0.f);
                    ((float*)Cv)[(size_t)z * sC + (size_t)gm * ldc + gn] = val;
                } else if (EPI == 1) {
                    ((ushort*)Cv)[(size_t)z * sC + (size_t)gm * ldc + gn] = f2bf(val);
                } else { // 2
                    int b = (gm >= NPAD) ? 1 : 0;
                    int i = gm - b * NPAD;
                    int which = gn >> 9, hh = (gn >> 6) & 7, d = gn & 63;
                    size_t dst = ((size_t)(b * 8 + hh) * NPAD + i) * 64 + d;
                    if (which == 0)      qp[dst] = f2bf(val * 0.125f);
                    else if (which == 1) kp[dst] = f2bf(val);
                    else                 vp[dst] = f2bf(val);
                }
            }
        }
    }
}

// =====================================================================
// Fused attn1: per 128 q-rows, S=q@kl^T (K=64) -> in-register softmax
// (rows live in a 16-lane group; defer-normalize) -> P (unnormalized exp,
// bf16) to per-wave LDS (XOR-swizzled) -> out = P@W (K=256) scaled by
// 1/rowsum, scattered to ot layout. kl/Wt B-frags read direct (L2-hot).
// No __syncthreads: each wave touches only its own 32 P rows.
// =====================================================================
__global__ __launch_bounds__(256)
void attn1_fused(const ushort* __restrict__ q, const ushort* __restrict__ kl,
                 const ushort* __restrict__ Wt, ushort* __restrict__ ot)
{
    __shared__ __align__(16) char P_s[128 * 512];   // 64 KB -> 2 blocks/CU
    const int mt = blockIdx.x;       // 0..47
    const int bh = blockIdx.y;       // 0..15
    const int b = bh >> 3, hh = bh & 7;
    const int tid = threadIdx.x, wid = tid >> 6, lane = tid & 63;
    const int lr = lane & 15, kg = lane >> 4;
    const int row0 = mt * 128;
    const ushort* qb  = q  + (size_t)bh * NPAD * 64;
    const ushort* klb = kl + (size_t)bh * LMK * 64;
    const ushort* Wtb = Wt + (size_t)bh * 128 * 256;

    // ---- phase 1: S = q @ kl^T, acc[mf][nf], rows wid*32+mf*16+kg*4+r ----
    f4_t acc[2][16];
#pragma unroll
    for (int mf = 0; mf < 2; ++mf)
#pragma unroll
        for (int nf = 0; nf < 16; ++nf) acc[mf][nf] = (f4_t){0.f, 0.f, 0.f, 0.f};
#pragma unroll
    for (int ks = 0; ks < 2; ++ks) {
        bf8_t af[2];
#pragma unroll
        for (int mf = 0; mf < 2; ++mf)
            af[mf] = *(const bf8_t*)&qb[(size_t)(row0 + wid * 32 + mf * 16 + lr) * 64 + ks * 32 + kg * 8];
#pragma unroll
        for (int nf = 0; nf < 16; ++nf) {
            bf8_t bg = *(const bf8_t*)&klb[(size_t)(nf * 16 + lr) * 64 + ks * 32 + kg * 8];
            acc[0][nf] = __builtin_amdgcn_mfma_f32_16x16x32_bf16(af[0], bg, acc[0][nf], 0, 0, 0);
            acc[1][nf] = __builtin_amdgcn_mfma_f32_16x16x32_bf16(af[1], bg, acc[1][nf], 0, 0, 0);
        }
    }
    // ---- in-register softmax (rows of 256 = 16 lanes x 16 regs) ----
    float inv_s[2][4];
#pragma unroll
    for (int mf = 0; mf < 2; ++mf) {
        float mx[4] = {-1e30f, -1e30f, -1e30f, -1e30f};
#pragma unroll
        for (int nf = 0; nf < 16; ++nf)
#pragma unroll
            for (int r = 0; r < 4; ++r) mx[r] = fmaxf(mx[r], acc[mf][nf][r]);
#pragma unroll
        for (int r = 0; r < 4; ++r) {
            mx[r] = fmaxf(mx[r], __shfl_xor(mx[r], 1, 64));
            mx[r] = fmaxf(mx[r], __shfl_xor(mx[r], 2, 64));
            mx[r] = fmaxf(mx[r], __shfl_xor(mx[r], 4, 64));
            mx[r] = fmaxf(mx[r], __shfl_xor(mx[r], 8, 64));
        }
        float sum[4] = {0.f, 0.f, 0.f, 0.f};
        const int rowb = wid * 32 + mf * 16 + kg * 4;
        const int cc2 = (lr & 7) * 2;           // within-chunk byte offset
        const int chi = lr >> 3;
#pragma unroll
        for (int nf = 0; nf < 16; ++nf) {
#pragma unroll
            for (int r = 0; r < 4; ++r) {
                float e = expf(acc[mf][nf][r] - mx[r]);
                sum[r] += e;
                int row = rowb + r;
                int chunk = (2 * nf + chi) ^ (row & 7);
                *(ushort*)(P_s + row * 512 + chunk * 16 + cc2) = f2bf(e);
            }
        }
#pragma unroll
        for (int r = 0; r < 4; ++r) {
            sum[r] += __shfl_xor(sum[r], 1, 64);
            sum[r] += __shfl_xor(sum[r], 2, 64);
            sum[r] += __shfl_xor(sum[r], 4, 64);
            sum[r] += __shfl_xor(sum[r], 8, 64);
            inv_s[mf][r] = 1.f / sum[r];
        }
    }
    // ---- phase 2: out = P @ W  (K=256); W^T rows direct from global ----
    f4_t acc2[2][4] = {};
#pragma unroll
    for (int kt = 0; kt < 8; ++kt) {
        bf8_t af2[2];
#pragma unroll
        for (int mf = 0; mf < 2; ++mf) {
            int row = wid * 32 + mf * 16 + lr;
            int chunk = (kt * 4 + kg) ^ (row & 7);
            af2[mf] = *(const bf8_t*)(P_s + row * 512 + chunk * 16);
        }
#pragma unroll
        for (int nf = 0; nf < 4; ++nf) {
            bf8_t bg = *(const bf8_t*)&Wtb[(size_t)(nf * 16 + lr) * 256 + kt * 32 + kg * 8];
            acc2[0][nf] = __builtin_amdgcn_mfma_f32_16x16x32_bf16(af2[0], bg, acc2[0][nf], 0, 0, 0);
            acc2[1][nf] = __builtin_amdgcn_mfma_f32_16x16x32_bf16(af2[1], bg, acc2[1][nf], 0, 0, 0);
        }
    }
    // ---- epilogue: normalize, scatter to ot[b][i][hh*64+d] ----
#pragma unroll
    for (int mf = 0; mf < 2; ++mf)
#pragma unroll
        for (int nf = 0; nf < 4; ++nf)
#pragma unroll
            for (int r = 0; r < 4; ++r) {
                int gm = row0 + wid * 32 + mf * 16 + kg * 4 + r;
                int gn = nf * 16 + lr;
                ot[((size_t)(b * NPAD + gm)) * DIMC + hh * 64 + gn] =
                    f2bf(acc2[mf][nf][r] * inv_s[mf][r]);
            }
}

// =====================================================================
// Small bf16 GEMM for Newton-Schulz: bf16 in/out, f32 accum.
// C = alpha*(A@B) [opt], C2 = c2d*I - alpha*A@B [opt], CT = (alpha*A@B)^T [opt].
// A [M][K] bf16 (lda=K), B [K][N] bf16 (ldb=N). 64x64 tile, 4 waves.
// =====================================================================
__global__ __launch_bounds__(256)
void gemm_ns(const ushort* __restrict__ A, const ushort* __restrict__ B,
             ushort* __restrict__ C, ushort* __restrict__ C2, ushort* __restrict__ CT,
             float alpha, float c2d, int K, int N,
             long long sA, long long sB, long long sC, long long sCT)
{
    __shared__ __align__(16) char As_s[64 * 64];
    __shared__ __align__(16) char Bs_s[64 * 64];
    const int z = blockIdx.z;
    const int row0 = blockIdx.y * 64, col0 = blockIdx.x * 64;
    const int tid = threadIdx.x;
    const int wid = tid >> 6, lane = tid & 63;
    const int lr = lane & 15, kg = lane >> 4;
    const ushort* Ab = A + (size_t)z * sA;
    const ushort* Bb = B + (size_t)z * sB;
    f4_t acc[4] = {};
    const int am = tid >> 2, ac8 = (tid & 3) * 8;
    for (int k0 = 0; k0 < K; k0 += 32) {
        *(bf8_t*)(As_s + SWZB(am, ac8)) = *(const bf8_t*)&Ab[(size_t)(row0 + am) * K + k0 + ac8];
#pragma unroll
        for (int p = 0; p < 8; ++p) {
            int kk = p * 4 + (tid >> 6), n = tid & 63;
            *(ushort*)(Bs_s + SWZB(n, kk)) = Bb[(size_t)(k0 + kk) * N + col0 + n];
        }
        __syncthreads();
        bf8_t af = *(const bf8_t*)(As_s + SWZB(wid * 16 + lr, kg * 8));
#pragma unroll
        for (int j = 0; j < 4; ++j) {
            bf8_t bg = *(const bf8_t*)(Bs_s + SWZB(j * 16 + lr, kg * 8));
            acc[j] = __builtin_amdgcn_mfma_f32_16x16x32_bf16(af, bg, acc[j], 0, 0, 0);
        }
        __syncthreads();
    }
#pragma unroll
    for (int j = 0; j < 4; ++j) {
#pragma unroll
        for (int r = 0; r < 4; ++r) {
            int gm = row0 + wid * 16 + kg * 4 + r;
            int gn = col0 + j * 16 + lr;
            float val = alpha * acc[j][r];
            if (C)  C[(size_t)z * sC + (size_t)gm * N + gn] = f2bf(val);
            if (C2) C2[(size_t)z * sC + (size_t)gm * N + gn] = f2bf(((gm == gn) ? c2d : 0.f) - val);
            if (CT) CT[(size_t)z * sCT + (size_t)gn * LMK + gm] = f2bf(val);
        }
    }
}

// =====================================================================
// attn3 PV split-K: o2p[split][bh][256][64] = P[256, kslice] @ v[kslice, 64]
// =====================================================================
__global__ __launch_bounds__(256)
void pv_splitk(const ushort* __restrict__ S, const ushort* __restrict__ v,
               float* __restrict__ o2p)
{
    __shared__ __align__(16) char As_s[128 * 64];
    __shared__ __align__(16) char Bs_s[64 * 64];
    const int split = blockIdx.x, mt = blockIdx.y, bh = blockIdx.z;
    const int tid = threadIdx.x;
    const int wid = tid >> 6, lane = tid & 63;
    const int lr = lane & 15, kg = lane >> 4;
    const ushort* Sb = S + (size_t)bh * LMK * NPAD + (size_t)(mt * 128) * NPAD;
    const ushort* vb = v + (size_t)bh * NPAD * 64;
    const int ks0 = split * (NPAD / KSPL);
    f4_t acc[2][4] = {};
    for (int k0 = ks0; k0 < ks0 + NPAD / KSPL; k0 += 32) {
#pragma unroll
        for (int p = 0; p < 2; ++p) {
            int idx = p * 256 + tid;
            int m = idx >> 2, kc = (idx & 3) * 8;
            *(bf8_t*)(As_s + SWZB(m, kc)) = *(const bf8_t*)&Sb[(size_t)m * NPAD + k0 + kc];
        }
#pragma unroll
        for (int p = 0; p < 8; ++p) {
            int kk = p * 4 + (tid >> 6), n = tid & 63;
            *(ushort*)(Bs_s + SWZB(n, kk)) = vb[(size_t)(k0 + kk) * 64 + n];
        }
        __syncthreads();
        bf8_t af[2], bg[4];
#pragma unroll
        for (int i = 0; i < 2; ++i)
            af[i] = *(const bf8_t*)(As_s + SWZB(wid * 32 + i * 16 + lr, kg * 8));
#pragma unroll
        for (int j = 0; j < 4; ++j)
            bg[j] = *(const bf8_t*)(Bs_s + SWZB(j * 16 + lr, kg * 8));
#pragma unroll
        for (int i = 0; i < 2; ++i)
#pragma unroll
            for (int j = 0; j < 4; ++j)
                acc[i][j] = __builtin_amdgcn_mfma_f32_16x16x32_bf16(af[i], bg[j], acc[i][j], 0, 0, 0);
        __syncthreads();
    }
#pragma unroll
    for (int i = 0; i < 2; ++i)
#pragma unroll
        for (int j = 0; j < 4; ++j)
#pragma unroll
            for (int r = 0; r < 4; ++r) {
                int gm = mt * 128 + wid * 32 + i * 16 + kg * 4 + r;
                int gn = j * 16 + lr;
                o2p[((size_t)(split * BHN + bh) * LMK + gm) * 64 + gn] = acc[i][j][r];
            }
}

__global__ void reduce_o2(const float* __restrict__ o2p, ushort* __restrict__ o2) {
    int idx = blockIdx.x * 256 + threadIdx.x;   // < BHN*LMK*64
    int bh = idx >> 14, e = idx & 16383;
    float s = 0.f;
#pragma unroll
    for (int sp = 0; sp < KSPL; ++sp)
        s += o2p[((size_t)(sp * BHN + bh) << 14) + e];
    o2[idx] = f2bf(s);
}

// ---------------- small kernels ----------------
__global__ void cvt_bf16(const float* __restrict__ in, ushort* __restrict__ out, int n8) {
    int i = blockIdx.x * 256 + threadIdx.x;
    if (i >= n8) return;
    float4 a = ((const float4*)in)[i * 2], b = ((const float4*)in)[i * 2 + 1];
    ushort4 lo = { f2bf(a.x), f2bf(a.y), f2bf(a.z), f2bf(a.w) };
    ushort4 hi = { f2bf(b.x), f2bf(b.y), f2bf(b.z), f2bf(b.w) };
    ((ushort4*)out)[i * 2] = lo;
    ((ushort4*)out)[i * 2 + 1] = hi;
}

__global__ void extend_h(float* __restrict__ h, const float* __restrict__ cls) {
    int b = blockIdx.y, bx = blockIdx.x; // 0 -> cls, 1..84 -> copy
    float* hb = h + (size_t)b * SEQ * DIMC;
    for (int c = threadIdx.x; c < DIMC; c += 256) {
        if (bx == 0) hb[c] = cls[c];
        else hb[(size_t)(6000 + bx) * DIMC + c] = hb[(size_t)bx * DIMC + c];
    }
}

__global__ void zero_xp_pad(ushort* __restrict__ xp) {
    int e = blockIdx.x * 256 + threadIdx.x;   // 2*59*512
    int b = e / (PADF * DIMC);
    int rest = e - b * (PADF * DIMC);
    xp[(size_t)b * NPAD * DIMC + rest] = 0;
}

__global__ __launch_bounds__(128)
void ln_to_xp(const float* __restrict__ h, const float* __restrict__ g,
              const float* __restrict__ bb, ushort* __restrict__ xp)
{
    __shared__ float sm[2];
    int r = blockIdx.x;            // 0 .. 2*6085-1
    int b = r / SEQ, i = r - b * SEQ;
    int t = threadIdx.x;
    const float4* row = (const float4*)(h + (size_t)r * DIMC);
    float4 x = row[t];
    float s  = x.x + x.y + x.z + x.w;
    float sq = x.x * x.x + x.y * x.y + x.z * x.z + x.w * x.w;
    s = waveSum(s);
    sq = waveSum(sq);
    int w = t >> 6;
    if ((t & 63) == 0) sm[w] = s;
    __syncthreads();
    float S = sm[0] + sm[1];
    __syncthreads();
    if ((t & 63) == 0) sm[w] = sq;
    __syncthreads();
    float SQ = sm[0] + sm[1];
    float mu = S * (1.f / DIMC);
    float var = SQ * (1.f / DIMC) - mu * mu;
    float rs = rsqrtf(var + 1e-5f);
    float4 gg = ((const float4*)g)[t];
    float4 bv = ((const float4*)bb)[t];
    ushort4 o;
    o.x = f2bf((x.x - mu) * rs * gg.x + bv.x);
    o.y = f2bf((x.y - mu) * rs * gg.y + bv.y);
    o.z = f2bf((x.z - mu) * rs * gg.z + bv.z);
    o.w = f2bf((x.w - mu) * rs * gg.w + bv.w);
    ((ushort4*)(xp + ((size_t)b * NPAD + PADF + i) * DIMC))[t] = o;
}

__global__ void landmark_mean(const ushort* __restrict__ in, ushort* __restrict__ out) {
    int m = blockIdx.x, bh = blockIdx.y, d = threadIdx.x;   // 64 threads
    const ushort* p = in + ((size_t)bh * NPAD + (size_t)m * (NPAD / LMK)) * 64 + d;
    float s = 0.f;
#pragma unroll
    for (int j = 0; j < NPAD / LMK; ++j) s += bf2f(p[(size_t)j * 64]);
    out[((size_t)bh * LMK + m) * 64 + d] = f2bf(s * (1.f / (NPAD / LMK)));
}

__global__ __launch_bounds__(256)
void softmax_bf_wide(ushort* __restrict__ S) {   // bf16, rows of 6144
    __shared__ float sm[4];
    ushort* p = S + (size_t)blockIdx.x * NPAD;
    int t = threadIdx.x;
    float v[24];
    float mx = -1e30f;
#pragma unroll
    for (int j = 0; j < 24; ++j) { v[j] = bf2f(p[j * 256 + t]); mx = fmaxf(mx, v[j]); }
    float bm = blockMax256(mx, sm);
    float s = 0.f;
#pragma unroll
    for (int j = 0; j < 24; ++j) { v[j] = expf(v[j] - bm); s += v[j]; }
    float bs = blockSum256(s, sm);
    float inv = 1.f / bs;
#pragma unroll
    for (int j = 0; j < 24; ++j) p[j * 256 + t] = f2bf(v[j] * inv);
}

__global__ __launch_bounds__(256)
void softmax_bf256(ushort* __restrict__ S) {     // bf16, rows of 256
    __shared__ float sm[4];
    ushort* p = S + (size_t)blockIdx.x * 256;
    int t = threadIdx.x;
    float v = bf2f(p[t]);
    float bm = blockMax256(v, sm);
    float e = expf(v - bm);
    float bs = blockSum256(e, sm);
    p[t] = f2bf(e / bs);
}

// max over (bh, j) of column sums of X[bh][:, j]; 16 blocks -> 16 atomics.
// (row-sum factor of softmax rows is identically 1.0, so only colsum needed)
__global__ __launch_bounds__(256)
void colsum_max(const ushort* __restrict__ X, float* __restrict__ scal) {
    __shared__ float sm[4];
    int bh = blockIdx.x, t = threadIdx.x;
    const ushort* Xb = X + ((size_t)bh << 16);
    float s = 0.f;
#pragma unroll 8
    for (int i = 0; i < 256; ++i) s += bf2f(Xb[(size_t)i * 256 + t]);
    float m = blockMax256(s, sm);
    if (t == 0) atomicMax((unsigned int*)scal, __float_as_uint(m));
}

__global__ void init_z(const ushort* __restrict__ X, const float* __restrict__ scal,
                       ushort* __restrict__ Z) {
    size_t e = (size_t)blockIdx.x * 256 + threadIdx.x;  // < 16*65536
    int c = (int)(e & 255);
    int r = (int)((e >> 8) & 255);
    size_t bh = e >> 16;
    float inv = 1.f / scal[0];
    Z[e] = f2bf(bf2f(X[(bh << 16) + (size_t)c * 256 + r]) * inv);
}

// depthwise conv residual with LDS v-tile
__global__ __launch_bounds__(256)
void conv_add(const ushort* __restrict__ v, const float* __restrict__ cw,
              ushort* __restrict__ ot)
{
    __shared__ float w[33];
    __shared__ ushort vt[96][64];
    int bh = blockIdx.y;
    int b = bh >> 3, hh = bh & 7;
    int i0 = blockIdx.x * 64;
    int t = threadIdx.x;
    if (t < 33) w[t] = cw[hh * 33 + t];
    const ushort* vb = v + (size_t)bh * NPAD * 64;
    int d = t & 63;
    for (int rr = t >> 6; rr < 96; rr += 4) {
        int j = i0 - 16 + rr;
        vt[rr][d] = (j >= 0 && j < NPAD) ? vb[(size_t)j * 64 + d] : (ushort)0;
    }
    __syncthreads();
    for (int ii = t >> 6; ii < 64; ii += 4) {
        float acc = 0.f;
#pragma unroll
        for (int kk = 0; kk < 33; ++kk) acc += w[kk] * bf2f(vt[ii + kk][d]);
        size_t off = ((size_t)(b * NPAD + i0 + ii)) * DIMC + hh * 64 + d;
        ot[off] = f2bf(bf2f(ot[off]) + acc);
    }
}

__global__ void residual_add(float* __restrict__ h, const float* __restrict__ y) {
    size_t e = (size_t)blockIdx.x * 256 + threadIdx.x;   // < 2*6085*512
    int c = (int)(e & 511);
    size_t ri = e >> 9;
    int i = (int)(ri % SEQ);
    int b = (int)(ri / SEQ);
    h[e] += y[((size_t)b * NPAD + PADF + i) * DIMC + c];
}

__global__ __launch_bounds__(256)
void final_head(const float* __restrict__ h, const float* __restrict__ g,
                const float* __restrict__ bb, const float* __restrict__ w2,
                const float* __restrict__ b2, float* __restrict__ out)
{
    __shared__ float row[DIMC];
    __shared__ float sm[4];
    int b = blockIdx.x;
    int t = threadIdx.x;
    const float* x = h + (size_t)b * SEQ * DIMC;  // CLS row
    float v0 = x[t], v1 = x[t + 256];
    float S = blockSum256(v0 + v1, sm);
    float SQ = blockSum256(v0 * v0 + v1 * v1, sm);
    float mu = S * (1.f / DIMC);
    float rs = rsqrtf(SQ * (1.f / DIMC) - mu * mu + 1e-5f);
    row[t] = (v0 - mu) * rs * g[t] + bb[t];
    row[t + 256] = (v1 - mu) * rs * g[t + 256] + bb[t + 256];
    __syncthreads();
    if (t < 64) {
        float a0 = 0.f, a1 = 0.f;
        for (int idx = t; idx < DIMC; idx += 64) {
            a0 += row[idx] * w2[idx];
            a1 += row[idx] * w2[DIMC + idx];
        }
        a0 = waveSum(a0);
        a1 = waveSum(a1);
        if (t == 0) {
            out[b * 2 + 0] = a0 + b2[0];
            out[b * 2 + 1] = a1 + b2[1];
        }
    }
}

// ---------------- host helpers ----------------
void bt(int epi, const ushort* A, const ushort* B, void* C, int M, int N, int K,
        int lda, int ldb, int ldc, long long sA, long long sB, long long sC, int batch,
        const float* bias, int relu, ushort* qp, ushort* kp, ushort* vp, hipStream_t s)
{
    dim3 g((N + 127) / 128, (M + 127) / 128, batch), blk(256);
    switch (epi) {
    case 0: gemm_bt<0><<<g, blk, 0, s>>>(A, B, C, M, N, K, lda, ldb, ldc, sA, sB, sC, bias, relu, qp, kp, vp); break;
    case 1: gemm_bt<1><<<g, blk, 0, s>>>(A, B, C, M, N, K, lda, ldb, ldc, sA, sB, sC, bias, relu, qp, kp, vp); break;
    default: gemm_bt<2><<<g, blk, 0, s>>>(A, B, C, M, N, K, lda, ldb, ldc, sA, sB, sC, bias, relu, qp, kp, vp); break;
    }
}

void ns(const ushort* A, const ushort* B, ushort* C, ushort* C2, ushort* CT,
        float alpha, float c2d, int M, int N, int K,
        long long sA, long long sB, long long sC, long long sCT, hipStream_t s)
{
    dim3 g(N / 64, M / 64, BHN), blk(256);
    gemm_ns<<<g, blk, 0, s>>>(A, B, C, C2, CT, alpha, c2d, K, N, sA, sB, sC, sCT);
}

struct WS {
    float *h, *scal, *o2p, *y;
    ushort *xp, *q, *k, *v, *ql, *kl;
    ushort *datab, *w1b, *qkvwb1, *qkvwb2, *outwb1, *outwb2;
    ushort *X, *Z0, *Z1, *XZ, *TA, *TB, *TC;
    ushort *o2b, *Wt, *S, *ot;
};

void nystrom_layer(float* h, const float* lng, const float* lnb,
                   const ushort* qkvwb, const ushort* outwb, const float* outb,
                   const float* convw, const WS& w, hipStream_t s)
{
    const long long SM = (long long)LMK * LMK;
    // LN -> padded xp (bf16)
    zero_xp_pad<<<(2 * PADF * DIMC) / 256, 256, 0, s>>>(w.xp);
    ln_to_xp<<<2 * SEQ, 128, 0, s>>>(h, lng, lnb, w.xp);
    // qkv = xp @ Wqkv^T, fused split-scatter into bf16 q (scaled), k, v
    bt(2, w.xp, qkvwb, nullptr, 2 * NPAD, 3 * DIMC, DIMC, DIMC, DIMC, 0,
       0, 0, 0, 1, nullptr, 0, w.q, w.k, w.v, s);
    landmark_mean<<<dim3(LMK, BHN), 64, 0, s>>>(w.q, w.ql);
    landmark_mean<<<dim3(LMK, BHN), 64, 0, s>>>(w.k, w.kl);
    // attn2 = softmax(q_l @ k_l^T)  -> X bf16
    bt(1, w.ql, w.kl, w.X, LMK, LMK, 64, 64, 64, LMK,
       (long long)LMK * 64, (long long)LMK * 64, SM, BHN, nullptr, 0, nullptr, nullptr, nullptr, s);
    softmax_bf256<<<BHN * LMK, 256, 0, s>>>(w.X);
    hipMemsetAsync(w.scal, 0, 8, s);
    colsum_max<<<BHN, 256, 0, s>>>(w.X, w.scal);
    init_z<<<(BHN * LMK * LMK) / 256, 256, 0, s>>>(w.X, w.scal, w.Z0);
    // Newton-Schulz (batched bf16 MFMA, diag fused)
    ushort* Zc = w.Z0;
    ushort* Zn = w.Z1;
    for (int it = 0; it < 6; ++it) {
        ns(w.X, Zc, w.XZ, w.TA, nullptr, 1.f, 7.f, LMK, LMK, LMK, SM, SM, SM, 0, s);
        ns(w.XZ, w.TA, w.TB, w.TC, nullptr, 1.f, 15.f, LMK, LMK, LMK, SM, SM, SM, 0, s);
        ns(w.XZ, w.TC, w.TB, w.TA, nullptr, 1.f, 13.f, LMK, LMK, LMK, SM, SM, SM, 0, s);
        ns(Zc, w.TA, Zn, nullptr, nullptr, 0.25f, 0.f, LMK, LMK, LMK, SM, SM, SM, 0, s);
        ushort* t = Zc; Zc = Zn; Zn = t;
    }
    // ---- attn3: S = q_l @ k^T (bf16), softmax, o2 = P @ v (split-K) ----
    bt(1, w.ql, w.k, w.S, LMK, NPAD, 64, 64, 64, NPAD,
       (long long)LMK * 64, (long long)NPAD * 64, (long long)LMK * NPAD, BHN,
       nullptr, 0, nullptr, nullptr, nullptr, s);
    softmax_bf_wide<<<BHN * LMK, 256, 0, s>>>(w.S);
    pv_splitk<<<dim3(KSPL, 2, BHN), 256, 0, s>>>(w.S, w.v, w.o2p);
    reduce_o2<<<BHN * LMK * 64 / 256, 256, 0, s>>>(w.o2p, w.o2b);
    // Wt = (pinv @ o2)^T  (bf16, padded to 128 rows per bh)
    ns(Zc, w.o2b, nullptr, nullptr, w.Wt, 1.f, 0.f, LMK, 64, LMK,
       SM, (long long)LMK * 64, 0, 128 * 256, s);
    // ---- attn1 fused: softmax(q @ k_l^T) @ W -> ot ----
    attn1_fused<<<dim3(NPAD / 128, BHN), 256, 0, s>>>(w.q, w.kl, w.Wt, w.ot);
    // + depthwise conv(v)
    conv_add<<<dim3(NPAD / 64, BHN), 256, 0, s>>>(w.v, convw, w.ot);
    // out proj -> y f32 (overlays S region, S dead)
    bt(0, w.ot, outwb, w.y, 2 * NPAD, DIMC, DIMC, DIMC, DIMC, DIMC,
       0, 0, 0, 1, outb, 0, nullptr, nullptr, nullptr, s);
    // h += y[:, PADF:]
    residual_add<<<(2 * SEQ * DIMC) / 256, 256, 0, s>>>(h, w.y);
}

} // namespace

extern "C" void kernel_launch(void* const* d_in, const int* in_sizes, int n_in,
                              void* d_out, int out_size, void* d_ws, size_t ws_size,
                              hipStream_t stream)
{
    (void)in_sizes; (void)n_in; (void)out_size;
    const float* data  = (const float*)d_in[0];
    const float* w1    = (const float*)d_in[1];
    const float* b1    = (const float*)d_in[2];
    const float* cls   = (const float*)d_in[3];
    const float* ln1g  = (const float*)d_in[4];
    const float* ln1b  = (const float*)d_in[5];
    const float* qkv1w = (const float*)d_in[6];
    const float* out1w = (const float*)d_in[7];
    const float* out1b = (const float*)d_in[8];
    const float* conv1 = (const float*)d_in[9];
    const float* ln2g  = (const float*)d_in[10];
    const float* ln2b  = (const float*)d_in[11];
    const float* qkv2w = (const float*)d_in[12];
    const float* out2w = (const float*)d_in[13];
    const float* out2b = (const float*)d_in[14];
    const float* conv2 = (const float*)d_in[15];
    const float* lnfg  = (const float*)d_in[16];
    const float* lnfb  = (const float*)d_in[17];
    const float* w2    = (const float*)d_in[18];
    const float* b2    = (const float*)d_in[19];
    float* out = (float*)d_out;

    if (ws_size < 209473792ull) return;
    char* p = (char*)d_ws;
    auto alloc = [&](size_t bytes) { char* r = p; p += (bytes + 255) & ~(size_t)255; return r; };
    WS w;
    w.h     = (float*)alloc((size_t)2 * SEQ * DIMC * 4);
    w.xp    = (ushort*)alloc((size_t)2 * NPAD * DIMC * 2);
    w.q     = (ushort*)alloc((size_t)BHN * NPAD * 64 * 2);
    w.k     = (ushort*)alloc((size_t)BHN * NPAD * 64 * 2);   // ot overlay
    w.v     = (ushort*)alloc((size_t)BHN * NPAD * 64 * 2);
    w.ql    = (ushort*)alloc((size_t)BHN * LMK * 64 * 2);
    w.kl    = (ushort*)alloc((size_t)BHN * LMK * 64 * 2);
    w.scal  = (float*)alloc(256);
    w.datab = (ushort*)alloc((size_t)2 * MPADR * 1024 * 2);
    w.w1b   = (ushort*)alloc((size_t)512 * 1024 * 2);
    w.qkvwb1= (ushort*)alloc((size_t)1536 * 512 * 2);
    w.qkvwb2= (ushort*)alloc((size_t)1536 * 512 * 2);
    w.outwb1= (ushort*)alloc((size_t)512 * 512 * 2);
    w.outwb2= (ushort*)alloc((size_t)512 * 512 * 2);
    w.X     = (ushort*)alloc((size_t)BHN * LMK * LMK * 2);
    w.Z0    = (ushort*)alloc((size_t)BHN * LMK * LMK * 2);
    w.Z1    = (ushort*)alloc((size_t)BHN * LMK * LMK * 2);
    w.XZ    = (ushort*)alloc((size_t)BHN * LMK * LMK * 2);
    w.TA    = (ushort*)alloc((size_t)BHN * LMK * LMK * 2);
    w.TB    = (ushort*)alloc((size_t)BHN * LMK * LMK * 2);
    w.TC    = (ushort*)alloc((size_t)BHN * LMK * LMK * 2);
    w.o2p   = (float*)alloc((size_t)KSPL * BHN * LMK * 64 * 4);
    w.o2b   = (ushort*)alloc((size_t)BHN * LMK * 64 * 2);
    w.Wt    = (ushort*)alloc((size_t)BHN * 128 * 256 * 2);
    w.S     = (ushort*)alloc((size_t)BHN * LMK * NPAD * 2);
    w.y     = (float*)w.S;   // out-proj output overlays S (dead by then)
    w.ot    = w.k;           // ot overlays k (dead after attn3 scores)

    // ---- one-time per-call bf16 conversions ----
    for (int b = 0; b < 2; ++b)
        cvt_bf16<<<3000, 256, 0, stream>>>(data + (size_t)b * 6000 * 1024,
                                           w.datab + (size_t)b * MPADR * 1024, 768000);
    cvt_bf16<<<256, 256, 0, stream>>>(w1, w.w1b, 65536);
    cvt_bf16<<<384, 256, 0, stream>>>(qkv1w, w.qkvwb1, 98304);
    cvt_bf16<<<384, 256, 0, stream>>>(qkv2w, w.qkvwb2, 98304);
    cvt_bf16<<<128, 256, 0, stream>>>(out1w, w.outwb1, 32768);
    cvt_bf16<<<128, 256, 0, stream>>>(out2w, w.outwb2, 32768);

    // fc1: h[b, 1+i, :] = relu(data[b,i,:] @ w1^T + b1)
    bt(0, w.datab, w.w1b, w.h + DIMC, 6000, DIMC, 1024, 1024, 1024, DIMC,
       (long long)MPADR * 1024, 0, (long long)SEQ * DIMC, 2, b1, 1,
       nullptr, nullptr, nullptr, stream);
    extend_h<<<dim3(85, 2), 256, 0, stream>>>(w.h, cls);

    nystrom_layer(w.h, ln1g, ln1b, w.qkvwb1, w.outwb1, out1b, conv1, w, stream);
    nystrom_layer(w.h, ln2g, ln2b, w.qkvwb2, w.outwb2, out2b, conv2, w, stream);

    final_head<<<2, 256, 0, stream>>>(w.h, lnfg, lnfb, w2, b2, out);
}